// Round 2
// baseline (3016.732 us; speedup 1.0000x reference)
//
#include <hip/hip_runtime.h>
#include <hip/hip_bf16.h>
#include <stdint.h>

typedef long long ll;

// ---------------- adjacency build (deterministic constant) ----------------
__device__ __forceinline__ float adj_unnorm(int r, int i, int j){
  bool im = (i>=22 && i<110);
  if (r==0){
    if (i<22) return (j>=22+i*4 && j<22+i*4+4) ? 1.f : 0.f;
    if (im){ int e=(i-22)>>2; return (j==e)?1.f:0.f; }
    return 0.f;
  } else if (r==1){
    if (im){ int e=(i-22)>>2; int base=22+e*4; return (j>=base && j<base+4 && j!=i)?1.f:0.f; }
    return 0.f;
  } else {
    if (im){ return (j == 110 + ((i-22)&15)) ? 1.f : 0.f; }
    if (i>=110){ return (j>=22 && j<110 && ((j-22)&15)==(i-110)) ? 1.f : 0.f; }
    return 0.f;
  }
}

__global__ void k_adj(float* __restrict__ adj){
  int r = blockIdx.x/126, i = blockIdx.x%126;
  int j = threadIdx.x;
  float v = (j<126)? adj_unnorm(r,i,j) : 0.f;
  __shared__ float red[128];
  red[j]=v; __syncthreads();
  for (int s=64;s>0;s>>=1){ if (j<s) red[j]+=red[j+s]; __syncthreads(); }
  if (j<126) adj[(r*126+i)*126 + j] = v / (red[0]+1e-5f);
}

// ---------------- generic fp32 GEMM 64x64x16, epilogue bias/bn/relu ----------------
template<bool RELU>
__global__ __launch_bounds__(256) void gemm_ep(
    const float* __restrict__ A, const float* __restrict__ B, float* __restrict__ C,
    int M, int N, int K, ll sA, ll sB, ll sC,
    const float* __restrict__ biasM, const float* __restrict__ gM,
    const float* __restrict__ beM, const float* __restrict__ biasN)
{
  int b = blockIdx.z;
  A += sA*b; B += sB*b; C += sC*b;
  __shared__ float As[16][68];
  __shared__ float Bs[16][68];
  int tid = threadIdx.x;
  int m0 = blockIdx.y*64, n0 = blockIdx.x*64;
  int tx = tid & 15, ty = tid >> 4;
  int la_m = tid>>2, la_k = (tid&3)<<2;
  int lb_k = tid>>4, lb_n = (tid&15)<<2;
  float acc[4][4] = {};
  for (int k0=0;k0<K;k0+=16){
    int gm = m0 + la_m;
    float4 av; av.x=av.y=av.z=av.w=0.f;
    if (gm < M) av = *reinterpret_cast<const float4*>(A + (ll)gm*K + k0 + la_k);
    As[la_k+0][la_m]=av.x; As[la_k+1][la_m]=av.y; As[la_k+2][la_m]=av.z; As[la_k+3][la_m]=av.w;
    int gn = n0 + lb_n;
    float4 bv; bv.x=bv.y=bv.z=bv.w=0.f;
    if (gn < N) bv = *reinterpret_cast<const float4*>(B + (ll)(k0+lb_k)*N + gn); // N%4==0 for all uses
    Bs[lb_k][lb_n+0]=bv.x; Bs[lb_k][lb_n+1]=bv.y; Bs[lb_k][lb_n+2]=bv.z; Bs[lb_k][lb_n+3]=bv.w;
    __syncthreads();
    #pragma unroll
    for (int kk=0;kk<16;kk++){
      float4 a4 = *reinterpret_cast<const float4*>(&As[kk][ty<<2]);
      float4 b4 = *reinterpret_cast<const float4*>(&Bs[kk][tx<<2]);
      float aa[4]={a4.x,a4.y,a4.z,a4.w}, bb[4]={b4.x,b4.y,b4.z,b4.w};
      #pragma unroll
      for (int i2=0;i2<4;i2++)
        #pragma unroll
        for (int j2=0;j2<4;j2++) acc[i2][j2] += aa[i2]*bb[j2];
    }
    __syncthreads();
  }
  #pragma unroll
  for (int i2=0;i2<4;i2++){
    int gm = m0 + (ty<<2) + i2;
    if (gm >= M) continue;
    float bm = biasM? biasM[gm] : 0.f;
    #pragma unroll
    for (int j2=0;j2<4;j2++){
      int gn = n0 + (tx<<2) + j2;
      if (gn >= N) continue;
      float v = acc[i2][j2] + bm;
      if (biasN) v += biasN[gn];
      if (gM) v = v*gM[gm] + beM[gm];
      if (RELU) v = fmaxf(v, 0.f);
      C[(ll)gm*N + gn] = v;
    }
  }
}

// ---------------- 5x5 SAME conv on 22x22, implicit GEMM (fp32 out) ----------------
__global__ __launch_bounds__(256) void conv5(
    const float* __restrict__ in, const float* __restrict__ w,
    const float* __restrict__ bias, float* __restrict__ outF, int O, int Cin)
{
  int b = blockIdx.z;
  const float* inb = in + (ll)b*Cin*484;
  int K = Cin*25;
  __shared__ float As[16][68];
  __shared__ float Bs[16][68];
  int tid = threadIdx.x;
  int m0 = blockIdx.y*64, n0 = blockIdx.x*64;
  int tx = tid & 15, ty = tid >> 4;
  int la_m = tid>>2, la_k = (tid&3)<<2;
  int lb_k = tid>>4, lb_n = (tid&15)<<2;
  int py[4], px[4]; bool pv[4];
  #pragma unroll
  for (int q=0;q<4;q++){
    int p = n0 + lb_n + q;
    pv[q] = (p < 484);
    int pp = pv[q]? p : 0;
    py[q] = pp/22; px[q] = pp%22;
  }
  float acc[4][4] = {};
  for (int k0=0;k0<K;k0+=16){
    int gm = m0 + la_m; // O%64==0 -> always valid
    float4 av = *reinterpret_cast<const float4*>(w + (ll)gm*K + k0 + la_k);
    As[la_k+0][la_m]=av.x; As[la_k+1][la_m]=av.y; As[la_k+2][la_m]=av.z; As[la_k+3][la_m]=av.w;
    int k = k0 + lb_k;
    int c = k/25, r = k%25;
    int ky = r/5 - 2, kx = r%5 - 2;
    const float* cin = inb + (ll)c*484;
    #pragma unroll
    for (int q=0;q<4;q++){
      int iy = py[q]+ky, ix = px[q]+kx;
      float v = 0.f;
      if (pv[q] && iy>=0 && iy<22 && ix>=0 && ix<22) v = cin[iy*22+ix];
      Bs[lb_k][lb_n+q] = v;
    }
    __syncthreads();
    #pragma unroll
    for (int kk=0;kk<16;kk++){
      float4 a4 = *reinterpret_cast<const float4*>(&As[kk][ty<<2]);
      float4 b4 = *reinterpret_cast<const float4*>(&Bs[kk][tx<<2]);
      float aa[4]={a4.x,a4.y,a4.z,a4.w}, bb[4]={b4.x,b4.y,b4.z,b4.w};
      #pragma unroll
      for (int i2=0;i2<4;i2++)
        #pragma unroll
        for (int j2=0;j2<4;j2++) acc[i2][j2] += aa[i2]*bb[j2];
    }
    __syncthreads();
  }
  #pragma unroll
  for (int i2=0;i2<4;i2++){
    int gm = m0 + (ty<<2) + i2;
    float bm = bias[gm];
    #pragma unroll
    for (int j2=0;j2<4;j2++){
      int gn = n0 + (tx<<2) + j2;
      if (gn >= 484) continue;
      float v = fmaxf(acc[i2][j2] + bm, 0.f);
      outF[((ll)b*O + gm)*484 + gn] = v;
    }
  }
}

// ---------------- node feature kernels ----------------
__global__ void k_ent(const float* __restrict__ seq, const int* __restrict__ midx, float* __restrict__ h0){
  int n = blockIdx.x/22, e = blockIdx.x%22;
  int rows[4];
  #pragma unroll
  for (int m=0;m<4;m++) rows[m] = midx[(n*22+e)*4+m];
  for (int d=threadIdx.x; d<512; d+=256){
    float v[4]; float mx = -1e30f;
    #pragma unroll
    for (int m=0;m<4;m++){
      v[m] = seq[((ll)n*1024+rows[m])*512 + d];
      h0[((ll)n*126+22+e*4+m)*532 + d] = v[m];
      mx = fmaxf(mx, v[m]);
    }
    float s = 0.f;
    #pragma unroll
    for (int m=0;m<4;m++) s += expf(v[m]-mx);
    h0[((ll)n*126+e)*532 + d] = mx + logf(s);
  }
}

__global__ void k_link(const float* __restrict__ att, const float* __restrict__ seq,
                       const int* __restrict__ ls_, float* __restrict__ h0){
  int n = blockIdx.x/16, l = blockIdx.x%16;
  int ls = ls_[n*16+l];
  int t = threadIdx.x; int tt = t>>3, lane = t&7;
  __shared__ float part[32][8];
  __shared__ float wv[32];
  float acc = 0.f;
  for (int i=lane; i<384; i+=8){
    int h = i>>5, s = i&31;
    acc += att[((ll)(n*12+h)*1024 + ls+s)*1024 + (ls+tt)];
  }
  part[tt][lane] = acc; __syncthreads();
  if (lane==0){
    float s2=0.f;
    #pragma unroll
    for (int q=0;q<8;q++) s2 += part[tt][q];
    wv[tt] = s2*(1.f/12.f);
  }
  __syncthreads();
  for (int d=t; d<512; d+=256){
    float a2 = 0.f;
    for (int tk=0;tk<32;tk++) a2 += wv[tk]*seq[((ll)n*1024+ls+tk)*512 + d];
    h0[((ll)n*126+110+l)*532 + d] = a2*(1.f/32.f);
  }
}

__global__ void k_tfeat(const float* __restrict__ te, float* __restrict__ h0){
  int idx = blockIdx.x*256 + threadIdx.x;
  if (idx >= 4*126*20) return;
  int t = idx%20; int i = (idx/20)%126; int n = idx/(20*126);
  int ty = (i<22)?0:((i<110)?1:2);
  h0[((ll)n*126+i)*532 + 512 + t] = te[ty*20+t];
}

__global__ void k_ea(const float* __restrict__ att, const int* __restrict__ midx, float* __restrict__ ea){
  int n = blockIdx.x/22, e = blockIdx.x%22;
  int t = threadIdx.x;
  __shared__ float vals[1024];
  __shared__ float red[256];
  int rows[4];
  #pragma unroll
  for (int m=0;m<4;m++) rows[m] = midx[(n*22+e)*4+m];
  float local = 0.f;
  for (int c=t; c<1024; c+=256){
    float acc = 0.f;
    #pragma unroll
    for (int m=0;m<4;m++){
      const float* base = att + ((ll)n*12*1024 + rows[m])*1024 + c;
      for (int h=0;h<12;h++) acc += base[(ll)h*1024*1024];
    }
    acc *= (1.f/48.f);
    vals[c] = acc; local += acc;
  }
  red[t] = local; __syncthreads();
  for (int s=128;s>0;s>>=1){ if (t<s) red[t]+=red[t+s]; __syncthreads(); }
  float denom = red[0] + 1e-5f;
  for (int c=t; c<1024; c+=256) ea[((ll)n*22+e)*1024 + c] = vals[c]/denom;
}

// ---------------- RGCN helpers ----------------
__global__ void k_copy2(const float* __restrict__ A, const float* __restrict__ B,
                        float* __restrict__ dst, int nA, int total){
  int idx = blockIdx.x*256 + threadIdx.x;
  if (idx < total) dst[idx] = (idx < nA) ? A[idx] : B[idx-nA];
}

__global__ void k_buildX(const float* __restrict__ adj, const float* __restrict__ h,
                         float* __restrict__ X, int Din){
  int n = blockIdx.x/126, i = blockIdx.x%126;
  int ld = 4*Din;
  for (int d=threadIdx.x; d<Din; d+=256){
    float hh = h[((ll)n*126+i)*Din + d];
    for (int r=0;r<3;r++){
      const float* arow = adj + (r*126+i)*126;
      float acc = 0.f;
      for (int j=0;j<126;j++){
        float a = arow[j];
        if (a != 0.f) acc += a * h[((ll)n*126+j)*Din + d];
      }
      X[((ll)n*126+i)*ld + r*Din + d] = acc;
    }
    X[((ll)n*126+i)*ld + 3*Din + d] = hh;
  }
}

// ---------------- pairwise map / SE / fuse ----------------
__global__ void k_ec(const float* __restrict__ hfin, const float* __restrict__ ectx, float* __restrict__ ec){
  int idx = blockIdx.x*256 + threadIdx.x; // 45056 exact
  int d = idx & 511; int e = (idx>>9)%22; int n = idx/(22*512);
  ec[idx] = hfin[((ll)n*126+e)*512 + d] + ectx[idx];
}

__global__ void k_fmap(const float* __restrict__ ec, float* __restrict__ fmap){
  int idx = blockIdx.x*256 + threadIdx.x; // 991232 exact
  int p = idx % 484; int d = (idx/484) & 511; int n = idx/(484*512);
  int i = p/22, j = p%22;
  fmap[idx] = ec[((ll)n*22+i)*512+d] * ec[((ll)n*22+j)*512+d];
}

__global__ void k_pool(const float* __restrict__ ec, float* __restrict__ pooled){
  int idx = blockIdx.x*256 + threadIdx.x;
  if (idx >= 2048) return;
  int n = idx>>9, c = idx&511;
  float s = 0.f;
  for (int i=0;i<22;i++) s += ec[((ll)n*22+i)*512 + c];
  pooled[idx] = s*s*(1.f/484.f);
}

__global__ void k_cb(const float* __restrict__ pooled,
                     const float* __restrict__ w1, const float* __restrict__ b1,
                     const float* __restrict__ g1, const float* __restrict__ be1,
                     const float* __restrict__ w2, const float* __restrict__ b2,
                     const float* __restrict__ g2, const float* __restrict__ be2,
                     float* __restrict__ cb){
  int n = blockIdx.x; int t = threadIdx.x;
  __shared__ float ps[512], t1[256];
  for (int c=t; c<512; c+=256) ps[c] = pooled[n*512+c];
  __syncthreads();
  {
    float acc = 0.f;
    for (int c=0;c<512;c++) acc += w1[t*512+c]*ps[c];
    float v = g1[t]*(acc+b1[t]) + be1[t];
    t1[t] = fmaxf(v, 0.f);
  }
  __syncthreads();
  for (int o=t; o<512; o+=256){
    float acc = 0.f;
    for (int c=0;c<256;c++) acc += w2[o*256+c]*t1[c];
    cb[n*512+o] = g2[o]*(acc+b2[o]) + be2[o];
  }
}

__global__ void k_fused(float* __restrict__ fmap, const float* __restrict__ sb, const float* __restrict__ cbv){
  int idx = blockIdx.x*256 + threadIdx.x; // 991232 exact
  int d = (idx/484) & 511; int n = idx/(484*512);
  float sv = sb[idx] + cbv[n*512+d];
  float sg = 1.f/(1.f + expf(-sv));
  fmap[idx] = fmap[idx]*sg;
}

// ---------------- launcher ----------------
extern "C" void kernel_launch(void* const* d_in, const int* in_sizes, int n_in,
                              void* d_out, int out_size, void* d_ws, size_t ws_size,
                              hipStream_t stream)
{
  (void)in_sizes; (void)n_in; (void)out_size; (void)ws_size;
  const float* seqout   = (const float*)d_in[0];
  const float* att      = (const float*)d_in[1];
  const float* W_trans  = (const float*)d_in[2];
  const float* b_trans  = (const float*)d_in[3];
  const float* type_emb = (const float*)d_in[4];
  const float* Wrel0    = (const float*)d_in[5];
  const float* Wself0   = (const float*)d_in[6];
  const float* Wrel     = (const float*)d_in[7];
  const float* Wself    = (const float*)d_in[8];
  const float* fs_w1    = (const float*)d_in[9];
  const float* fs_b1    = (const float*)d_in[10];
  const float* fs_g1    = (const float*)d_in[11];
  const float* fs_be1   = (const float*)d_in[12];
  const float* fs_w2    = (const float*)d_in[13];
  const float* fs_b2    = (const float*)d_in[14];
  const float* fs_g2    = (const float*)d_in[15];
  const float* fs_be2   = (const float*)d_in[16];
  const float* fc_w1    = (const float*)d_in[17];
  const float* fc_b1    = (const float*)d_in[18];
  const float* fc_g1    = (const float*)d_in[19];
  const float* fc_be1   = (const float*)d_in[20];
  const float* fc_w2    = (const float*)d_in[21];
  const float* fc_b2    = (const float*)d_in[22];
  const float* fc_g2    = (const float*)d_in[23];
  const float* fc_be2   = (const float*)d_in[24];
  const float* cr_w1    = (const float*)d_in[25];
  const float* cr_b1    = (const float*)d_in[26];
  const float* cr_w2    = (const float*)d_in[27];
  const float* cr_b2    = (const float*)d_in[28];
  const float* cr_w3    = (const float*)d_in[29];
  const float* cr_b3    = (const float*)d_in[30];
  const int*   midx     = (const int*)d_in[31];
  const int*   lstart   = (const int*)d_in[32];
  float* out            = (float*)d_out;   // reference output dtype is float32

  float* ws = (float*)d_ws;
  size_t off = 0;
  auto alloc = [&](size_t nelem)->float*{ float* p = ws + off; off += (nelem + 15) & ~(size_t)15; return p; };
  float* adj   = alloc((size_t)3*126*126);
  float* seq   = alloc((size_t)4096*512);
  float* h0    = alloc((size_t)504*532);
  float* ea    = alloc((size_t)88*1024);
  float* ectx  = alloc((size_t)88*512);
  float* X     = alloc((size_t)504*2128);
  float* Wcat  = alloc((size_t)2128*512);
  float* hA    = alloc((size_t)504*512);
  float* hB    = alloc((size_t)504*512);
  float* ec    = alloc((size_t)88*512);
  float* fmap  = alloc((size_t)4*512*484);
  float* s1b   = alloc((size_t)4*256*484);
  float* sb    = alloc((size_t)4*512*484);
  float* pooled= alloc(2048);
  float* cbv   = alloc(2048);
  float* r1    = alloc((size_t)4*256*484);
  float* r2    = alloc((size_t)4*256*484);

  // constants
  k_adj<<<378,128,0,stream>>>(adj);
  // seq = seqout @ W_trans + b_trans  (4096x768 @ 768x512)
  gemm_ep<false><<<dim3(8,64,1),256,0,stream>>>(seqout, W_trans, seq, 4096,512,768, 0,0,0,
                                                nullptr,nullptr,nullptr, b_trans);
  // node features
  k_ent <<<88,256,0,stream>>>(seq, midx, h0);
  k_link<<<64,256,0,stream>>>(att, seq, lstart, h0);
  k_tfeat<<<40,256,0,stream>>>(type_emb, h0);
  k_ea  <<<88,256,0,stream>>>(att, midx, ea);
  // e_ctx = ea @ seq (batched, 22x1024 @ 1024x512)
  gemm_ep<false><<<dim3(8,1,4),256,0,stream>>>(ea, seq, ectx, 22,512,1024,
                                               (ll)22*1024, (ll)1024*512, (ll)22*512,
                                               nullptr,nullptr,nullptr,nullptr);
  // RGCN layer 0 (Din=532)
  k_copy2<<<4256,256,0,stream>>>(Wrel0, Wself0, Wcat, 3*532*512, 2128*512);
  k_buildX<<<504,256,0,stream>>>(adj, h0, X, 532);
  gemm_ep<true><<<dim3(8,8,1),256,0,stream>>>(X, Wcat, hA, 504,512,2128, 0,0,0,
                                              nullptr,nullptr,nullptr,nullptr);
  // RGCN layers 1..3 (Din=512)
  float* hcur = hA; float* hnxt = hB;
  for (int l=0;l<3;l++){
    k_copy2<<<4096,256,0,stream>>>(Wrel + (ll)l*3*512*512, Wself + (ll)l*512*512, Wcat,
                                   3*512*512, 2048*512);
    k_buildX<<<504,256,0,stream>>>(adj, hcur, X, 512);
    gemm_ep<true><<<dim3(8,8,1),256,0,stream>>>(X, Wcat, hnxt, 504,512,2048, 0,0,0,
                                                nullptr,nullptr,nullptr,nullptr);
    float* t = hcur; hcur = hnxt; hnxt = t;
  }
  // ec = h[:, :22] + e_ctx
  k_ec<<<176,256,0,stream>>>(hcur, ectx, ec);
  // fmap outer product
  k_fmap<<<3872,256,0,stream>>>(ec, fmap);
  // SE spatial branch: s1 = relu(bn1(w1@fmap + b1)); s = bn2(w2@s1 + b2)
  gemm_ep<true ><<<dim3(8,4,4),256,0,stream>>>(fs_w1, fmap, s1b, 256,484,512,
                                               0, (ll)512*484, (ll)256*484,
                                               fs_b1, fs_g1, fs_be1, nullptr);
  gemm_ep<false><<<dim3(8,8,4),256,0,stream>>>(fs_w2, s1b, sb, 512,484,256,
                                               0, (ll)256*484, (ll)512*484,
                                               fs_b2, fs_g2, fs_be2, nullptr);
  // SE channel branch
  k_pool<<<8,256,0,stream>>>(ec, pooled);
  k_cb<<<4,256,0,stream>>>(pooled, fc_w1, fc_b1, fc_g1, fc_be1,
                           fc_w2, fc_b2, fc_g2, fc_be2, cbv);
  // fused = fmap * sigmoid(s + cb)   (in-place into fmap)
  k_fused<<<3872,256,0,stream>>>(fmap, sb, cbv);
  // conv stack
  conv5<<<dim3(8,4,4),256,0,stream>>>(fmap, cr_w1, cr_b1, r1, 256, 512);
  conv5<<<dim3(8,4,4),256,0,stream>>>(r1,   cr_w2, cr_b2, r2, 256, 256);
  conv5<<<dim3(8,8,4),256,0,stream>>>(r2,   cr_w3, cr_b3, out, 512, 256);
}

// Round 3
// 1311.606 us; speedup vs baseline: 2.3000x; 2.3000x over previous
//
#include <hip/hip_runtime.h>
#include <hip/hip_bf16.h>
#include <stdint.h>

typedef long long ll;
typedef float f32x4 __attribute__((ext_vector_type(4)));
typedef __bf16 bf16x8 __attribute__((ext_vector_type(8)));
typedef __bf16 bf16x4 __attribute__((ext_vector_type(4)));

// ---------------- adjacency build (deterministic constant) ----------------
__device__ __forceinline__ float adj_unnorm(int r, int i, int j){
  bool im = (i>=22 && i<110);
  if (r==0){
    if (i<22) return (j>=22+i*4 && j<22+i*4+4) ? 1.f : 0.f;
    if (im){ int e=(i-22)>>2; return (j==e)?1.f:0.f; }
    return 0.f;
  } else if (r==1){
    if (im){ int e=(i-22)>>2; int base=22+e*4; return (j>=base && j<base+4 && j!=i)?1.f:0.f; }
    return 0.f;
  } else {
    if (im){ return (j == 110 + ((i-22)&15)) ? 1.f : 0.f; }
    if (i>=110){ return (j>=22 && j<110 && ((j-22)&15)==(i-110)) ? 1.f : 0.f; }
    return 0.f;
  }
}

__global__ void k_adj(float* __restrict__ adj){
  int r = blockIdx.x/126, i = blockIdx.x%126;
  int j = threadIdx.x;
  float v = (j<126)? adj_unnorm(r,i,j) : 0.f;
  __shared__ float red[128];
  red[j]=v; __syncthreads();
  for (int s=64;s>0;s>>=1){ if (j<s) red[j]+=red[j+s]; __syncthreads(); }
  if (j<126) adj[(r*126+i)*126 + j] = v / (red[0]+1e-5f);
}

// ---------------- generic fp32 GEMM 64x64x16, epilogue bias/bn/relu ----------------
template<bool RELU>
__global__ __launch_bounds__(256) void gemm_ep(
    const float* __restrict__ A, const float* __restrict__ B, float* __restrict__ C,
    int M, int N, int K, ll sA, ll sB, ll sC,
    const float* __restrict__ biasM, const float* __restrict__ gM,
    const float* __restrict__ beM, const float* __restrict__ biasN)
{
  int b = blockIdx.z;
  A += sA*b; B += sB*b; C += sC*b;
  __shared__ float As[16][68];
  __shared__ float Bs[16][68];
  int tid = threadIdx.x;
  int m0 = blockIdx.y*64, n0 = blockIdx.x*64;
  int tx = tid & 15, ty = tid >> 4;
  int la_m = tid>>2, la_k = (tid&3)<<2;
  int lb_k = tid>>4, lb_n = (tid&15)<<2;
  float acc[4][4] = {};
  for (int k0=0;k0<K;k0+=16){
    int gm = m0 + la_m;
    float4 av; av.x=av.y=av.z=av.w=0.f;
    if (gm < M) av = *reinterpret_cast<const float4*>(A + (ll)gm*K + k0 + la_k);
    As[la_k+0][la_m]=av.x; As[la_k+1][la_m]=av.y; As[la_k+2][la_m]=av.z; As[la_k+3][la_m]=av.w;
    int gn = n0 + lb_n;
    float4 bv; bv.x=bv.y=bv.z=bv.w=0.f;
    if (gn < N) bv = *reinterpret_cast<const float4*>(B + (ll)(k0+lb_k)*N + gn);
    Bs[lb_k][lb_n+0]=bv.x; Bs[lb_k][lb_n+1]=bv.y; Bs[lb_k][lb_n+2]=bv.z; Bs[lb_k][lb_n+3]=bv.w;
    __syncthreads();
    #pragma unroll
    for (int kk=0;kk<16;kk++){
      float4 a4 = *reinterpret_cast<const float4*>(&As[kk][ty<<2]);
      float4 b4 = *reinterpret_cast<const float4*>(&Bs[kk][tx<<2]);
      float aa[4]={a4.x,a4.y,a4.z,a4.w}, bb[4]={b4.x,b4.y,b4.z,b4.w};
      #pragma unroll
      for (int i2=0;i2<4;i2++)
        #pragma unroll
        for (int j2=0;j2<4;j2++) acc[i2][j2] += aa[i2]*bb[j2];
    }
    __syncthreads();
  }
  #pragma unroll
  for (int i2=0;i2<4;i2++){
    int gm = m0 + (ty<<2) + i2;
    if (gm >= M) continue;
    float bm = biasM? biasM[gm] : 0.f;
    #pragma unroll
    for (int j2=0;j2<4;j2++){
      int gn = n0 + (tx<<2) + j2;
      if (gn >= N) continue;
      float v = acc[i2][j2] + bm;
      if (biasN) v += biasN[gn];
      if (gM) v = v*gM[gm] + beM[gm];
      if (RELU) v = fmaxf(v, 0.f);
      C[(ll)gm*N + gn] = v;
    }
  }
}

// ---------------- MFMA bf16 5x5 conv on padded interleaved layout ----------------
// Activations: Xint[b][e][c], e = row*32+col over a 29x32 padded plane (stride 928
// elems/plane); real pixel (py,px) at e=(py+2)*32+(px+2). Weights: Wt[o][tap][c],
// tap=ky*5+kx. Output pixel p=py*32+px (py<24, garbage px>=22 / py>=22 discarded).
// out(p) = sum_{tap,c} Wt[o][tap][c] * Xint[p + ky*32 + kx][c].
template<int CIN, int OCHT, bool FINAL>
__global__ __launch_bounds__(256) void conv5_mfma(
    const __hip_bfloat16* __restrict__ Xg, const __hip_bfloat16* __restrict__ Wt,
    const float* __restrict__ bias, __hip_bfloat16* __restrict__ Xout,
    float* __restrict__ outF)
{
  __shared__ bf16x8 Xs8[272*32/8];   // [e_loc][32c] swizzled, 17408 B
  __shared__ bf16x8 Ws8[5*64*32/8];  // [tapL][64o][32c] swizzled, 20480 B
  char* xs = (char*)Xs8;
  char* wsm = (char*)Ws8;

  const int tid = threadIdx.x;
  const int l = tid & 63;
  const int l15 = l & 15, lg = l >> 4, lg16 = (l>>4)*16;
  const int w = tid >> 6;
  const int wave_o0 = (w>>1)*32;     // 0 or 32
  const int wave_p0 = (w&1)*64;      // 0 or 64
  const int b = blockIdx.z;
  const int p0 = blockIdx.x*128;     // pixel tile base (768/128 = 6 tiles)
  const int o0 = blockIdx.y*64;      // out-channel tile base

  // per-thread fragment row bases
  int orow0 = wave_o0 + l15;         // of=0 row within tile
  int orow1 = wave_o0 + 16 + l15;    // of=1
  int baseA0 = orow0*64 + (lg16 ^ (((orow0>>1)&3)<<4));
  int baseA1 = orow1*64 + (lg16 ^ (((orow1>>1)&3)<<4));
  int pl[4];
  #pragma unroll
  for (int pf=0; pf<4; ++pf) pl[pf] = wave_p0 + pf*16 + l15;  // local pixel col

  f32x4 acc[2][4] = {};

  const int NCB = CIN/32;
  for (int cblk=0; cblk<NCB; ++cblk){
    __syncthreads();
    // stage X: 272 e-rows x 32 ch = 1088 x 16B chunks
    #pragma unroll
    for (int i=0;i<5;i++){
      int idx = tid + i*256;
      if (idx < 1088){
        int e = idx>>2, c8 = idx&3;
        const __hip_bfloat16* g = Xg + ((size_t)(b*928 + p0 + e))*CIN + cblk*32 + c8*8;
        bf16x8 v = *reinterpret_cast<const bf16x8*>(g);
        int byte = e*64 + ((c8*16) ^ (((e>>1)&3)<<4));
        *reinterpret_cast<bf16x8*>(xs + byte) = v;
      }
    }
    for (int g5=0; g5<5; ++g5){
      if (g5>0) __syncthreads();
      // stage W: 5 taps x 64 o x 32 c = 1280 x 16B chunks
      #pragma unroll
      for (int i=0;i<5;i++){
        int idx = tid + i*256;
        int tapL = idx>>8, r = idx&255;
        int o = r>>2, c8 = r&3;
        const __hip_bfloat16* g = Wt + ((size_t)(o0+o)*25 + (g5*5+tapL))*CIN + cblk*32 + c8*8;
        bf16x8 v = *reinterpret_cast<const bf16x8*>(g);
        int byte = tapL*4096 + o*64 + ((c8*16) ^ (((o>>1)&3)<<4));
        *reinterpret_cast<bf16x8*>(wsm + byte) = v;
      }
      __syncthreads();
      #pragma unroll
      for (int tapL=0; tapL<5; ++tapL){
        bf16x8 a0 = *reinterpret_cast<const bf16x8*>(wsm + tapL*4096 + baseA0);
        bf16x8 a1 = *reinterpret_cast<const bf16x8*>(wsm + tapL*4096 + baseA1);
        int koff = g5*32 + tapL;
        #pragma unroll
        for (int pf=0; pf<4; ++pf){
          int e = pl[pf] + koff;
          bf16x8 bv = *reinterpret_cast<const bf16x8*>(xs + e*64 + (lg16 ^ (((e>>1)&3)<<4)));
          acc[0][pf] = __builtin_amdgcn_mfma_f32_16x16x32_bf16(a0, bv, acc[0][pf], 0,0,0);
          acc[1][pf] = __builtin_amdgcn_mfma_f32_16x16x32_bf16(a1, bv, acc[1][pf], 0,0,0);
        }
      }
    }
  }

  // epilogue: D col = lane&15 (pixel), row = (lane>>4)*4 + reg (out-channel)
  #pragma unroll
  for (int of=0; of<2; ++of){
    int og = o0 + wave_o0 + of*16 + lg*4;   // 4 consecutive out-channels
    float b0 = bias[og], b1 = bias[og+1], b2 = bias[og+2], b3 = bias[og+3];
    #pragma unroll
    for (int pf=0; pf<4; ++pf){
      int p = p0 + pl[pf];
      int py = p>>5, px = p&31;
      if (py>=22 || px>=22) continue;
      f32x4 a = acc[of][pf];
      float v0 = fmaxf(a[0]+b0, 0.f), v1 = fmaxf(a[1]+b1, 0.f);
      float v2 = fmaxf(a[2]+b2, 0.f), v3 = fmaxf(a[3]+b3, 0.f);
      if (FINAL){
        size_t base = ((size_t)b*OCHT + og)*484 + py*22 + px;
        outF[base] = v0; outF[base+484] = v1; outF[base+968] = v2; outF[base+1452] = v3;
      } else {
        union { bf16x4 v; uint2 u; } pk;
        pk.v[0] = (__bf16)v0; pk.v[1] = (__bf16)v1; pk.v[2] = (__bf16)v2; pk.v[3] = (__bf16)v3;
        int e = p + 66;  // (py+2)*32 + (px+2)
        *reinterpret_cast<uint2*>(Xout + ((size_t)(b*928 + e))*OCHT + og) = pk.u;
      }
    }
  }
}

// weight transpose: cr_w [O][C][25] fp32 -> Wt [O][25][C] bf16
__global__ void wt_make(const float* __restrict__ w, __hip_bfloat16* __restrict__ wt, int C){
  int o = blockIdx.x;
  for (int c=threadIdx.x; c<C; c+=256){
    const float* src = w + ((size_t)o*C + c)*25;
    float v[25];
    #pragma unroll
    for (int t=0;t<25;t++) v[t] = src[t];
    #pragma unroll
    for (int t=0;t<25;t++) wt[((size_t)o*25 + t)*C + c] = __float2bfloat16(v[t]);
  }
}

// ---------------- node feature kernels ----------------
__global__ void k_ent(const float* __restrict__ seq, const int* __restrict__ midx, float* __restrict__ h0){
  int n = blockIdx.x/22, e = blockIdx.x%22;
  int rows[4];
  #pragma unroll
  for (int m=0;m<4;m++) rows[m] = midx[(n*22+e)*4+m];
  for (int d=threadIdx.x; d<512; d+=256){
    float v[4]; float mx = -1e30f;
    #pragma unroll
    for (int m=0;m<4;m++){
      v[m] = seq[((ll)n*1024+rows[m])*512 + d];
      h0[((ll)n*126+22+e*4+m)*532 + d] = v[m];
      mx = fmaxf(mx, v[m]);
    }
    float s = 0.f;
    #pragma unroll
    for (int m=0;m<4;m++) s += expf(v[m]-mx);
    h0[((ll)n*126+e)*532 + d] = mx + logf(s);
  }
}

__global__ void k_link(const float* __restrict__ att, const float* __restrict__ seq,
                       const int* __restrict__ ls_, float* __restrict__ h0){
  int n = blockIdx.x/16, l = blockIdx.x%16;
  int ls = ls_[n*16+l];
  int t = threadIdx.x; int tt = t>>3, lane = t&7;
  __shared__ float part[32][8];
  __shared__ float wv[32];
  float acc = 0.f;
  for (int i=lane; i<384; i+=8){
    int h = i>>5, s = i&31;
    acc += att[((ll)(n*12+h)*1024 + ls+s)*1024 + (ls+tt)];
  }
  part[tt][lane] = acc; __syncthreads();
  if (lane==0){
    float s2=0.f;
    #pragma unroll
    for (int q=0;q<8;q++) s2 += part[tt][q];
    wv[tt] = s2*(1.f/12.f);
  }
  __syncthreads();
  for (int d=t; d<512; d+=256){
    float a2 = 0.f;
    for (int tk=0;tk<32;tk++) a2 += wv[tk]*seq[((ll)n*1024+ls+tk)*512 + d];
    h0[((ll)n*126+110+l)*532 + d] = a2*(1.f/32.f);
  }
}

__global__ void k_tfeat(const float* __restrict__ te, float* __restrict__ h0){
  int idx = blockIdx.x*256 + threadIdx.x;
  if (idx >= 4*126*20) return;
  int t = idx%20; int i = (idx/20)%126; int n = idx/(20*126);
  int ty = (i<22)?0:((i<110)?1:2);
  h0[((ll)n*126+i)*532 + 512 + t] = te[ty*20+t];
}

__global__ void k_ea(const float* __restrict__ att, const int* __restrict__ midx, float* __restrict__ ea){
  int n = blockIdx.x/22, e = blockIdx.x%22;
  int t = threadIdx.x;
  __shared__ float vals[1024];
  __shared__ float red[256];
  int rows[4];
  #pragma unroll
  for (int m=0;m<4;m++) rows[m] = midx[(n*22+e)*4+m];
  float local = 0.f;
  for (int c=t; c<1024; c+=256){
    float acc = 0.f;
    #pragma unroll
    for (int m=0;m<4;m++){
      const float* base = att + ((ll)n*12*1024 + rows[m])*1024 + c;
      for (int h=0;h<12;h++) acc += base[(ll)h*1024*1024];
    }
    acc *= (1.f/48.f);
    vals[c] = acc; local += acc;
  }
  red[t] = local; __syncthreads();
  for (int s=128;s>0;s>>=1){ if (t<s) red[t]+=red[t+s]; __syncthreads(); }
  float denom = red[0] + 1e-5f;
  for (int c=t; c<1024; c+=256) ea[((ll)n*22+e)*1024 + c] = vals[c]/denom;
}

// ---------------- RGCN helpers ----------------
__global__ void k_copy2(const float* __restrict__ A, const float* __restrict__ B,
                        float* __restrict__ dst, int nA, int total){
  int idx = blockIdx.x*256 + threadIdx.x;
  if (idx < total) dst[idx] = (idx < nA) ? A[idx] : B[idx-nA];
}

__global__ void k_buildX(const float* __restrict__ adj, const float* __restrict__ h,
                         float* __restrict__ X, int Din){
  int n = blockIdx.x/126, i = blockIdx.x%126;
  int ld = 4*Din;
  for (int d=threadIdx.x; d<Din; d+=256){
    float hh = h[((ll)n*126+i)*Din + d];
    for (int r=0;r<3;r++){
      const float* arow = adj + (r*126+i)*126;
      float acc = 0.f;
      for (int j=0;j<126;j++){
        float a = arow[j];
        if (a != 0.f) acc += a * h[((ll)n*126+j)*Din + d];
      }
      X[((ll)n*126+i)*ld + r*Din + d] = acc;
    }
    X[((ll)n*126+i)*ld + 3*Din + d] = hh;
  }
}

// ---------------- pairwise map / SE / fuse ----------------
__global__ void k_ec(const float* __restrict__ hfin, const float* __restrict__ ectx, float* __restrict__ ec){
  int idx = blockIdx.x*256 + threadIdx.x; // 45056 exact
  int d = idx & 511; int e = (idx>>9)%22; int n = idx/(22*512);
  ec[idx] = hfin[((ll)n*126+e)*512 + d] + ectx[idx];
}

__global__ void k_fmap(const float* __restrict__ ec, float* __restrict__ fmap){
  int idx = blockIdx.x*256 + threadIdx.x; // 991232 exact
  int p = idx % 484; int d = (idx/484) & 511; int n = idx/(484*512);
  int i = p/22, j = p%22;
  fmap[idx] = ec[((ll)n*22+i)*512+d] * ec[((ll)n*22+j)*512+d];
}

__global__ void k_pool(const float* __restrict__ ec, float* __restrict__ pooled){
  int idx = blockIdx.x*256 + threadIdx.x;
  if (idx >= 2048) return;
  int n = idx>>9, c = idx&511;
  float s = 0.f;
  for (int i=0;i<22;i++) s += ec[((ll)n*22+i)*512 + c];
  pooled[idx] = s*s*(1.f/484.f);
}

__global__ void k_cb(const float* __restrict__ pooled,
                     const float* __restrict__ w1, const float* __restrict__ b1,
                     const float* __restrict__ g1, const float* __restrict__ be1,
                     const float* __restrict__ w2, const float* __restrict__ b2,
                     const float* __restrict__ g2, const float* __restrict__ be2,
                     float* __restrict__ cb){
  int n = blockIdx.x; int t = threadIdx.x;
  __shared__ float ps[512], t1[256];
  for (int c=t; c<512; c+=256) ps[c] = pooled[n*512+c];
  __syncthreads();
  {
    float acc = 0.f;
    for (int c=0;c<512;c++) acc += w1[t*512+c]*ps[c];
    float v = g1[t]*(acc+b1[t]) + be1[t];
    t1[t] = fmaxf(v, 0.f);
  }
  __syncthreads();
  for (int o=t; o<512; o+=256){
    float acc = 0.f;
    for (int c=0;c<256;c++) acc += w2[o*256+c]*t1[c];
    cb[n*512+o] = g2[o]*(acc+b2[o]) + be2[o];
  }
}

// fused = fmap * sigmoid(s + cb), written channel-interleaved bf16 padded
__global__ void k_fused_b(const float* __restrict__ fmap, const float* __restrict__ sb,
                          const float* __restrict__ cbv, __hip_bfloat16* __restrict__ Xint1){
  int n = blockIdx.z; int d8 = blockIdx.y;
  int p = blockIdx.x*256 + threadIdx.x;
  if (p >= 484) return;
  int py = p/22, px = p%22;
  int e = (py+2)*32 + px + 2;
  size_t base = ((size_t)n*512 + d8*8)*484 + p;
  union { bf16x8 v; uint4 u; } pk;
  #pragma unroll
  for (int di=0; di<8; ++di){
    float fm = fmap[base + (size_t)di*484];
    float sv = sb[base + (size_t)di*484] + cbv[n*512 + d8*8 + di];
    float sg = 1.f/(1.f + expf(-sv));
    pk.v[di] = (__bf16)(fm*sg);
  }
  *reinterpret_cast<uint4*>(Xint1 + ((size_t)(n*928 + e))*512 + d8*8) = pk.u;
}

// ---------------- launcher ----------------
extern "C" void kernel_launch(void* const* d_in, const int* in_sizes, int n_in,
                              void* d_out, int out_size, void* d_ws, size_t ws_size,
                              hipStream_t stream)
{
  (void)in_sizes; (void)n_in; (void)out_size; (void)ws_size;
  const float* seqout   = (const float*)d_in[0];
  const float* att      = (const float*)d_in[1];
  const float* W_trans  = (const float*)d_in[2];
  const float* b_trans  = (const float*)d_in[3];
  const float* type_emb = (const float*)d_in[4];
  const float* Wrel0    = (const float*)d_in[5];
  const float* Wself0   = (const float*)d_in[6];
  const float* Wrel     = (const float*)d_in[7];
  const float* Wself    = (const float*)d_in[8];
  const float* fs_w1    = (const float*)d_in[9];
  const float* fs_b1    = (const float*)d_in[10];
  const float* fs_g1    = (const float*)d_in[11];
  const float* fs_be1   = (const float*)d_in[12];
  const float* fs_w2    = (const float*)d_in[13];
  const float* fs_b2    = (const float*)d_in[14];
  const float* fs_g2    = (const float*)d_in[15];
  const float* fs_be2   = (const float*)d_in[16];
  const float* fc_w1    = (const float*)d_in[17];
  const float* fc_b1    = (const float*)d_in[18];
  const float* fc_g1    = (const float*)d_in[19];
  const float* fc_be1   = (const float*)d_in[20];
  const float* fc_w2    = (const float*)d_in[21];
  const float* fc_b2    = (const float*)d_in[22];
  const float* fc_g2    = (const float*)d_in[23];
  const float* fc_be2   = (const float*)d_in[24];
  const float* cr_w1    = (const float*)d_in[25];
  const float* cr_b1    = (const float*)d_in[26];
  const float* cr_w2    = (const float*)d_in[27];
  const float* cr_b2    = (const float*)d_in[28];
  const float* cr_w3    = (const float*)d_in[29];
  const float* cr_b3    = (const float*)d_in[30];
  const int*   midx     = (const int*)d_in[31];
  const int*   lstart   = (const int*)d_in[32];
  float* out            = (float*)d_out;

  char* wsb = (char*)d_ws;
  size_t off = 0;
  auto allocB = [&](size_t nbytes)->char*{ char* p = wsb + off; off += (nbytes + 63) & ~(size_t)63; return p; };
  float* adj   = (float*)allocB(3*126*126*4);
  float* seq   = (float*)allocB((size_t)4096*512*4);
  float* h0    = (float*)allocB((size_t)504*532*4);
  float* ea    = (float*)allocB((size_t)88*1024*4);
  float* ectx  = (float*)allocB((size_t)88*512*4);
  float* X     = (float*)allocB((size_t)504*2128*4);
  float* Wcat  = (float*)allocB((size_t)2128*512*4);
  float* hA    = (float*)allocB((size_t)504*512*4);
  float* hB    = (float*)allocB((size_t)504*512*4);
  float* ec    = (float*)allocB((size_t)88*512*4);
  float* fmap  = (float*)allocB((size_t)4*512*484*4);
  float* s1b   = (float*)allocB((size_t)4*256*484*4);
  float* sb    = (float*)allocB((size_t)4*512*484*4);
  float* pooled= (float*)allocB(2048*4);
  float* cbv   = (float*)allocB(2048*4);
  __hip_bfloat16* Xint1 = (__hip_bfloat16*)allocB((size_t)4*928*512*2);
  __hip_bfloat16* Xint2 = (__hip_bfloat16*)allocB((size_t)4*928*256*2);
  __hip_bfloat16* Xint3 = (__hip_bfloat16*)allocB((size_t)4*928*256*2);
  __hip_bfloat16* Wt1   = (__hip_bfloat16*)allocB((size_t)256*25*512*2);
  __hip_bfloat16* Wt2   = (__hip_bfloat16*)allocB((size_t)256*25*256*2);
  __hip_bfloat16* Wt3   = (__hip_bfloat16*)allocB((size_t)512*25*256*2);

  // zero padded interleaved activation buffers (borders must be 0)
  hipMemsetAsync(Xint1, 0, (size_t)4*928*512*2, stream);
  hipMemsetAsync(Xint2, 0, (size_t)4*928*256*2, stream);
  hipMemsetAsync(Xint3, 0, (size_t)4*928*256*2, stream);

  // constants / weights prep
  k_adj<<<378,128,0,stream>>>(adj);
  wt_make<<<256,256,0,stream>>>(cr_w1, Wt1, 512);
  wt_make<<<256,256,0,stream>>>(cr_w2, Wt2, 256);
  wt_make<<<512,256,0,stream>>>(cr_w3, Wt3, 256);

  // seq = seqout @ W_trans + b_trans  (4096x768 @ 768x512)
  gemm_ep<false><<<dim3(8,64,1),256,0,stream>>>(seqout, W_trans, seq, 4096,512,768, 0,0,0,
                                                nullptr,nullptr,nullptr, b_trans);
  // node features
  k_ent <<<88,256,0,stream>>>(seq, midx, h0);
  k_link<<<64,256,0,stream>>>(att, seq, lstart, h0);
  k_tfeat<<<40,256,0,stream>>>(type_emb, h0);
  k_ea  <<<88,256,0,stream>>>(att, midx, ea);
  // e_ctx = ea @ seq (batched, 22x1024 @ 1024x512)
  gemm_ep<false><<<dim3(8,1,4),256,0,stream>>>(ea, seq, ectx, 22,512,1024,
                                               (ll)22*1024, (ll)1024*512, (ll)22*512,
                                               nullptr,nullptr,nullptr,nullptr);
  // RGCN layer 0 (Din=532)
  k_copy2<<<4256,256,0,stream>>>(Wrel0, Wself0, Wcat, 3*532*512, 2128*512);
  k_buildX<<<504,256,0,stream>>>(adj, h0, X, 532);
  gemm_ep<true><<<dim3(8,8,1),256,0,stream>>>(X, Wcat, hA, 504,512,2128, 0,0,0,
                                              nullptr,nullptr,nullptr,nullptr);
  // RGCN layers 1..3 (Din=512)
  float* hcur = hA; float* hnxt = hB;
  for (int l=0;l<3;l++){
    k_copy2<<<4096,256,0,stream>>>(Wrel + (ll)l*3*512*512, Wself + (ll)l*512*512, Wcat,
                                   3*512*512, 2048*512);
    k_buildX<<<504,256,0,stream>>>(adj, hcur, X, 512);
    gemm_ep<true><<<dim3(8,8,1),256,0,stream>>>(X, Wcat, hnxt, 504,512,2048, 0,0,0,
                                                nullptr,nullptr,nullptr,nullptr);
    float* t = hcur; hcur = hnxt; hnxt = t;
  }
  // ec = h[:, :22] + e_ctx
  k_ec<<<176,256,0,stream>>>(hcur, ectx, ec);
  // fmap outer product (fp32, feeds SE branch)
  k_fmap<<<3872,256,0,stream>>>(ec, fmap);
  // SE spatial branch
  gemm_ep<true ><<<dim3(8,4,4),256,0,stream>>>(fs_w1, fmap, s1b, 256,484,512,
                                               0, (ll)512*484, (ll)256*484,
                                               fs_b1, fs_g1, fs_be1, nullptr);
  gemm_ep<false><<<dim3(8,8,4),256,0,stream>>>(fs_w2, s1b, sb, 512,484,256,
                                               0, (ll)256*484, (ll)512*484,
                                               fs_b2, fs_g2, fs_be2, nullptr);
  // SE channel branch
  k_pool<<<8,256,0,stream>>>(ec, pooled);
  k_cb<<<4,256,0,stream>>>(pooled, fc_w1, fc_b1, fc_g1, fc_be1,
                           fc_w2, fc_b2, fc_g2, fc_be2, cbv);
  // fused -> interleaved padded bf16
  k_fused_b<<<dim3(2,64,4),256,0,stream>>>(fmap, sb, cbv, Xint1);
  // conv stack (MFMA)
  conv5_mfma<512,256,false><<<dim3(6,4,4),256,0,stream>>>(Xint1, Wt1, cr_b1, Xint2, nullptr);
  conv5_mfma<256,256,false><<<dim3(6,4,4),256,0,stream>>>(Xint2, Wt2, cr_b2, Xint3, nullptr);
  conv5_mfma<256,512,true ><<<dim3(6,8,4),256,0,stream>>>(Xint3, Wt3, cr_b3, nullptr, out);
}

// Round 5
// 993.462 us; speedup vs baseline: 3.0366x; 1.3202x over previous
//
#include <hip/hip_runtime.h>
#include <hip/hip_bf16.h>
#include <stdint.h>

typedef long long ll;
typedef float f32x4 __attribute__((ext_vector_type(4)));
typedef __bf16 bf16x8 __attribute__((ext_vector_type(8)));
typedef __bf16 bf16x4 __attribute__((ext_vector_type(4)));

// ---------------- adjacency build ----------------
__device__ __forceinline__ float adj_unnorm(int r, int i, int j){
  bool im = (i>=22 && i<110);
  if (r==0){
    if (i<22) return (j>=22+i*4 && j<22+i*4+4) ? 1.f : 0.f;
    if (im){ int e=(i-22)>>2; return (j==e)?1.f:0.f; }
    return 0.f;
  } else if (r==1){
    if (im){ int e=(i-22)>>2; int base=22+e*4; return (j>=base && j<base+4 && j!=i)?1.f:0.f; }
    return 0.f;
  } else {
    if (im){ return (j == 110 + ((i-22)&15)) ? 1.f : 0.f; }
    if (i>=110){ return (j>=22 && j<110 && ((j-22)&15)==(i-110)) ? 1.f : 0.f; }
    return 0.f;
  }
}

__global__ void k_adj(float* __restrict__ adj){
  int r = blockIdx.x/126, i = blockIdx.x%126;
  int j = threadIdx.x;
  float v = (j<126)? adj_unnorm(r,i,j) : 0.f;
  __shared__ float red[128];
  red[j]=v; __syncthreads();
  for (int s=64;s>0;s>>=1){ if (j<s) red[j]+=red[j+s]; __syncthreads(); }
  if (j<126) adj[(r*126+i)*126 + j] = v / (red[0]+1e-5f);
}

// ---------------- casts ----------------
__global__ void k_cast_split(const float* __restrict__ in, __bf16* __restrict__ hi,
                             __bf16* __restrict__ lo, ll n){
  ll idx = (ll)blockIdx.x*256 + threadIdx.x;
  if (idx >= n) return;
  float x = in[idx];
  __bf16 h = (__bf16)x;
  hi[idx] = h; lo[idx] = (__bf16)(x - (float)h);
}
__global__ void k_cast_hi(const float* __restrict__ in, __bf16* __restrict__ hi, ll n){
  ll idx = (ll)blockIdx.x*256 + threadIdx.x;
  if (idx >= n) return;
  hi[idx] = (__bf16)in[idx];
}
// in [R][C] -> out [C][R] (split)
__global__ void k_castT_split(const float* __restrict__ in, __bf16* __restrict__ hi,
                              __bf16* __restrict__ lo, int R, int C){
  ll idx = (ll)blockIdx.x*256 + threadIdx.x;
  if (idx >= (ll)R*C) return;
  int r = (int)(idx % R); int c = (int)(idx / R);
  float x = in[(ll)r*C + c];
  __bf16 h = (__bf16)x;
  hi[idx] = h; lo[idx] = (__bf16)(x - (float)h);
}
// WcatT [512][Kpad]
__global__ void k_wcatT(const float* __restrict__ Wrel, const float* __restrict__ Wself,
                        __bf16* __restrict__ hi, __bf16* __restrict__ lo,
                        int Din, int Kpad){
  ll idx = (ll)blockIdx.x*256 + threadIdx.x;
  if (idx >= (ll)512*Kpad) return;
  int k = (int)(idx % Kpad); int o = (int)(idx / Kpad);
  float x = 0.f;
  if (k < 4*Din){
    int r = k / Din, d = k % Din;
    x = (r<3) ? Wrel[((ll)r*Din + d)*512 + o] : Wself[(ll)d*512 + o];
  }
  __bf16 h = (__bf16)x;
  hi[idx] = h; lo[idx] = (__bf16)(x - (float)h);
}

// ---------------- MFMA GEMM: A [M][K] bf16(hi/lo), B^T [N][K] bf16(hi/lo) ----------------
// tile: 64(M) x 128(N), K-step 32. 4 waves: wave = 32M x 64N (2x4 frags 16x16).
// MODE 0: Cf[M][N] = acc + biasN        (seq)
// MODE 1: Cf[M][N] = relu(acc)          (rgcn)
// MODE 2: Cb^T[N][M] = relu((acc+biasM)*g+be)  bf16 (se1)
// MODE 3: Cf[M][N] = (acc+biasM)*g+be   (se2)
template<int SPLIT, int MODE>
__global__ __launch_bounds__(256) void gemm_mfma(
    const __bf16* __restrict__ Ahi, const __bf16* __restrict__ Alo,
    const __bf16* __restrict__ Bhi, const __bf16* __restrict__ Blo,
    float* __restrict__ Cf, __bf16* __restrict__ Cb,
    int M, int N, int K, ll sB, ll sC,
    const float* __restrict__ biasN, const float* __restrict__ biasM,
    const float* __restrict__ gM, const float* __restrict__ beM)
{
  __shared__ char lds[24576];
  char* asH = lds;          // [64][32] bf16 = 4096B
  char* bsH = lds + 4096;   // [128][32] = 8192B
  char* asL = lds + 12288;
  char* bsL = lds + 16384;

  int b = blockIdx.z;
  Bhi += sB*b; if (SPLIT) Blo += sB*b;

  const int tid = threadIdx.x;
  const int l15 = tid & 15, lg = (tid&63)>>4, lg16 = ((tid&63)>>4)*16;
  const int w = tid >> 6;
  const int wave_m0 = (w>>1)*32, wave_n0 = (w&1)*64;
  const int m0 = blockIdx.y*64, n0 = blockIdx.x*128;

  const int sa_row = tid>>2, sa_c8 = tid&3;
  const int sa_byte = sa_row*64 + ((sa_c8*16) ^ (((sa_row>>1)&3)<<4));
  const int gmA = m0 + sa_row;

  int baseA[2], baseB[4];
  #pragma unroll
  for (int mf=0; mf<2; ++mf){
    int r = wave_m0 + mf*16 + l15;
    baseA[mf] = r*64 + (lg16 ^ (((r>>1)&3)<<4));
  }
  #pragma unroll
  for (int nf=0; nf<4; ++nf){
    int r = wave_n0 + nf*16 + l15;
    baseB[nf] = r*64 + (lg16 ^ (((r>>1)&3)<<4));
  }

  f32x4 acc[2][4] = {};

  for (int k0=0; k0<K; k0+=32){
    __syncthreads();
    {
      bf16x8 v = {};
      if (gmA < M) v = *reinterpret_cast<const bf16x8*>(Ahi + (ll)gmA*K + k0 + sa_c8*8);
      *reinterpret_cast<bf16x8*>(asH + sa_byte) = v;
      if (SPLIT){
        bf16x8 vl = {};
        if (gmA < M) vl = *reinterpret_cast<const bf16x8*>(Alo + (ll)gmA*K + k0 + sa_c8*8);
        *reinterpret_cast<bf16x8*>(asL + sa_byte) = vl;
      }
    }
    #pragma unroll
    for (int i=0;i<2;i++){
      int idx = tid + i*256;
      int row = idx>>2, c8 = idx&3;
      int gn = n0 + row;
      int byte = row*64 + ((c8*16) ^ (((row>>1)&3)<<4));
      bf16x8 v = {};
      if (gn < N) v = *reinterpret_cast<const bf16x8*>(Bhi + (ll)gn*K + k0 + c8*8);
      *reinterpret_cast<bf16x8*>(bsH + byte) = v;
      if (SPLIT){
        bf16x8 vl = {};
        if (gn < N) vl = *reinterpret_cast<const bf16x8*>(Blo + (ll)gn*K + k0 + c8*8);
        *reinterpret_cast<bf16x8*>(bsL + byte) = vl;
      }
    }
    __syncthreads();
    bf16x8 aH[2], bH[4];
    #pragma unroll
    for (int mf=0; mf<2; ++mf) aH[mf] = *reinterpret_cast<const bf16x8*>(asH + baseA[mf]);
    #pragma unroll
    for (int nf=0; nf<4; ++nf) bH[nf] = *reinterpret_cast<const bf16x8*>(bsH + baseB[nf]);
    if (SPLIT){
      bf16x8 aL[2], bL[4];
      #pragma unroll
      for (int mf=0; mf<2; ++mf) aL[mf] = *reinterpret_cast<const bf16x8*>(asL + baseA[mf]);
      #pragma unroll
      for (int nf=0; nf<4; ++nf) bL[nf] = *reinterpret_cast<const bf16x8*>(bsL + baseB[nf]);
      #pragma unroll
      for (int mf=0; mf<2; ++mf)
        #pragma unroll
        for (int nf=0; nf<4; ++nf){
          acc[mf][nf] = __builtin_amdgcn_mfma_f32_16x16x32_bf16(aH[mf], bH[nf], acc[mf][nf], 0,0,0);
          acc[mf][nf] = __builtin_amdgcn_mfma_f32_16x16x32_bf16(aH[mf], bL[nf], acc[mf][nf], 0,0,0);
          acc[mf][nf] = __builtin_amdgcn_mfma_f32_16x16x32_bf16(aL[mf], bH[nf], acc[mf][nf], 0,0,0);
        }
    } else {
      #pragma unroll
      for (int mf=0; mf<2; ++mf)
        #pragma unroll
        for (int nf=0; nf<4; ++nf)
          acc[mf][nf] = __builtin_amdgcn_mfma_f32_16x16x32_bf16(aH[mf], bH[nf], acc[mf][nf], 0,0,0);
    }
  }

  if (MODE==0 || MODE==1){
    float* C = Cf + sC*b;
    #pragma unroll
    for (int mf=0; mf<2; ++mf){
      int gmb = m0 + wave_m0 + mf*16 + lg*4;
      #pragma unroll
      for (int nf=0; nf<4; ++nf){
        int gn = n0 + wave_n0 + nf*16 + l15;
        if (gn >= N) continue;
        float bn_ = (MODE==0) ? biasN[gn] : 0.f;
        f32x4 a = acc[mf][nf];
        #pragma unroll
        for (int r=0;r<4;r++){
          int gm = gmb + r;
          if (gm < M){
            float v = a[r] + bn_;
            if (MODE==1) v = fmaxf(v, 0.f);
            C[(ll)gm*N + gn] = v;
          }
        }
      }
    }
  } else if (MODE==2){
    __bf16* C = Cb + sC*b;
    #pragma unroll
    for (int mf=0; mf<2; ++mf){
      int gmb = m0 + wave_m0 + mf*16 + lg*4;
      float b0=biasM[gmb], b1=biasM[gmb+1], b2=biasM[gmb+2], b3=biasM[gmb+3];
      float g0=gM[gmb], g1=gM[gmb+1], g2=gM[gmb+2], g3=gM[gmb+3];
      float e0=beM[gmb], e1=beM[gmb+1], e2=beM[gmb+2], e3=beM[gmb+3];
      #pragma unroll
      for (int nf=0; nf<4; ++nf){
        int gn = n0 + wave_n0 + nf*16 + l15;
        if (gn >= N) continue;
        f32x4 a = acc[mf][nf];
        union { bf16x4 v; uint2 u; } pk;
        pk.v[0] = (__bf16)fmaxf((a[0]+b0)*g0+e0, 0.f);
        pk.v[1] = (__bf16)fmaxf((a[1]+b1)*g1+e1, 0.f);
        pk.v[2] = (__bf16)fmaxf((a[2]+b2)*g2+e2, 0.f);
        pk.v[3] = (__bf16)fmaxf((a[3]+b3)*g3+e3, 0.f);
        *reinterpret_cast<uint2*>(C + (ll)gn*M + gmb) = pk.u;
      }
    }
  } else { // MODE 3
    float* C = Cf + sC*b;
    #pragma unroll
    for (int mf=0; mf<2; ++mf){
      int gmb = m0 + wave_m0 + mf*16 + lg*4;
      float b0=biasM[gmb], b1=biasM[gmb+1], b2=biasM[gmb+2], b3=biasM[gmb+3];
      float g0=gM[gmb], g1=gM[gmb+1], g2=gM[gmb+2], g3=gM[gmb+3];
      float e0=beM[gmb], e1=beM[gmb+1], e2=beM[gmb+2], e3=beM[gmb+3];
      #pragma unroll
      for (int nf=0; nf<4; ++nf){
        int gn = n0 + wave_n0 + nf*16 + l15;
        if (gn >= N) continue;
        f32x4 a = acc[mf][nf];
        C[(ll)(gmb+0)*N + gn] = (a[0]+b0)*g0+e0;
        C[(ll)(gmb+1)*N + gn] = (a[1]+b1)*g1+e1;
        C[(ll)(gmb+2)*N + gn] = (a[2]+b2)*g2+e2;
        C[(ll)(gmb+3)*N + gn] = (a[3]+b3)*g3+e3;
      }
    }
  }
}

// ---------------- fp32 GEMM (kept for small ectx) ----------------
template<bool RELU>
__global__ __launch_bounds__(256) void gemm_ep(
    const float* __restrict__ A, const float* __restrict__ B, float* __restrict__ C,
    int M, int N, int K, ll sA, ll sB, ll sC,
    const float* __restrict__ biasM, const float* __restrict__ gM,
    const float* __restrict__ beM, const float* __restrict__ biasN)
{
  int b = blockIdx.z;
  A += sA*b; B += sB*b; C += sC*b;
  __shared__ float As[16][68];
  __shared__ float Bs[16][68];
  int tid = threadIdx.x;
  int m0 = blockIdx.y*64, n0 = blockIdx.x*64;
  int tx = tid & 15, ty = tid >> 4;
  int la_m = tid>>2, la_k = (tid&3)<<2;
  int lb_k = tid>>4, lb_n = (tid&15)<<2;
  float acc[4][4] = {};
  for (int k0=0;k0<K;k0+=16){
    int gm = m0 + la_m;
    float4 av; av.x=av.y=av.z=av.w=0.f;
    if (gm < M) av = *reinterpret_cast<const float4*>(A + (ll)gm*K + k0 + la_k);
    As[la_k+0][la_m]=av.x; As[la_k+1][la_m]=av.y; As[la_k+2][la_m]=av.z; As[la_k+3][la_m]=av.w;
    int gn = n0 + lb_n;
    float4 bv; bv.x=bv.y=bv.z=bv.w=0.f;
    if (gn < N) bv = *reinterpret_cast<const float4*>(B + (ll)(k0+lb_k)*N + gn);
    Bs[lb_k][lb_n+0]=bv.x; Bs[lb_k][lb_n+1]=bv.y; Bs[lb_k][lb_n+2]=bv.z; Bs[lb_k][lb_n+3]=bv.w;
    __syncthreads();
    #pragma unroll
    for (int kk=0;kk<16;kk++){
      float4 a4 = *reinterpret_cast<const float4*>(&As[kk][ty<<2]);
      float4 b4 = *reinterpret_cast<const float4*>(&Bs[kk][tx<<2]);
      float aa[4]={a4.x,a4.y,a4.z,a4.w}, bb[4]={b4.x,b4.y,b4.z,b4.w};
      #pragma unroll
      for (int i2=0;i2<4;i2++)
        #pragma unroll
        for (int j2=0;j2<4;j2++) acc[i2][j2] += aa[i2]*bb[j2];
    }
    __syncthreads();
  }
  #pragma unroll
  for (int i2=0;i2<4;i2++){
    int gm = m0 + (ty<<2) + i2;
    if (gm >= M) continue;
    float bm = biasM? biasM[gm] : 0.f;
    #pragma unroll
    for (int j2=0;j2<4;j2++){
      int gn = n0 + (tx<<2) + j2;
      if (gn >= N) continue;
      float v = acc[i2][j2] + bm;
      if (biasN) v += biasN[gn];
      if (gM) v = v*gM[gm] + beM[gm];
      if (RELU) v = fmaxf(v, 0.f);
      C[(ll)gm*N + gn] = v;
    }
  }
}

// ---------------- MFMA bf16 5x5 conv ----------------
template<int CIN, int OCHT, bool FINAL>
__global__ __launch_bounds__(256) void conv5_mfma(
    const __bf16* __restrict__ Xg, const __bf16* __restrict__ Wt,
    const float* __restrict__ bias, __bf16* __restrict__ Xout,
    float* __restrict__ outF)
{
  __shared__ bf16x8 Xs8[272*32/8];
  __shared__ bf16x8 Ws8[5*64*32/8];
  char* xs = (char*)Xs8;
  char* wsm = (char*)Ws8;

  const int tid = threadIdx.x;
  const int l = tid & 63;
  const int l15 = l & 15, lg = l >> 4, lg16 = (l>>4)*16;
  const int w = tid >> 6;
  const int wave_o0 = (w>>1)*32;
  const int wave_p0 = (w&1)*64;
  const int b = blockIdx.z;
  const int p0 = blockIdx.x*128;
  const int o0 = blockIdx.y*64;

  int orow0 = wave_o0 + l15;
  int orow1 = wave_o0 + 16 + l15;
  int baseA0 = orow0*64 + (lg16 ^ (((orow0>>1)&3)<<4));
  int baseA1 = orow1*64 + (lg16 ^ (((orow1>>1)&3)<<4));
  int pl[4];
  #pragma unroll
  for (int pf=0; pf<4; ++pf) pl[pf] = wave_p0 + pf*16 + l15;

  f32x4 acc[2][4] = {};

  const int NCB = CIN/32;
  for (int cblk=0; cblk<NCB; ++cblk){
    __syncthreads();
    #pragma unroll
    for (int i=0;i<5;i++){
      int idx = tid + i*256;
      if (idx < 1088){
        int e = idx>>2, c8 = idx&3;
        const __bf16* g = Xg + ((size_t)(b*928 + p0 + e))*CIN + cblk*32 + c8*8;
        bf16x8 v = *reinterpret_cast<const bf16x8*>(g);
        int byte = e*64 + ((c8*16) ^ (((e>>1)&3)<<4));
        *reinterpret_cast<bf16x8*>(xs + byte) = v;
      }
    }
    for (int g5=0; g5<5; ++g5){
      if (g5>0) __syncthreads();
      #pragma unroll
      for (int i=0;i<5;i++){
        int idx = tid + i*256;
        int tapL = idx>>8, r = idx&255;
        int o = r>>2, c8 = r&3;
        const __bf16* g = Wt + ((size_t)(o0+o)*25 + (g5*5+tapL))*CIN + cblk*32 + c8*8;
        bf16x8 v = *reinterpret_cast<const bf16x8*>(g);
        int byte = tapL*4096 + o*64 + ((c8*16) ^ (((o>>1)&3)<<4));
        *reinterpret_cast<bf16x8*>(wsm + byte) = v;
      }
      __syncthreads();
      #pragma unroll
      for (int tapL=0; tapL<5; ++tapL){
        bf16x8 a0 = *reinterpret_cast<const bf16x8*>(wsm + tapL*4096 + baseA0);
        bf16x8 a1 = *reinterpret_cast<const bf16x8*>(wsm + tapL*4096 + baseA1);
        int koff = g5*32 + tapL;
        #pragma unroll
        for (int pf=0; pf<4; ++pf){
          int e = pl[pf] + koff;
          bf16x8 bv = *reinterpret_cast<const bf16x8*>(xs + e*64 + (lg16 ^ (((e>>1)&3)<<4)));
          acc[0][pf] = __builtin_amdgcn_mfma_f32_16x16x32_bf16(a0, bv, acc[0][pf], 0,0,0);
          acc[1][pf] = __builtin_amdgcn_mfma_f32_16x16x32_bf16(a1, bv, acc[1][pf], 0,0,0);
        }
      }
    }
  }

  #pragma unroll
  for (int of=0; of<2; ++of){
    int og = o0 + wave_o0 + of*16 + lg*4;
    float b0 = bias[og], b1 = bias[og+1], b2 = bias[og+2], b3 = bias[og+3];
    #pragma unroll
    for (int pf=0; pf<4; ++pf){
      int p = p0 + pl[pf];
      int py = p>>5, px = p&31;
      if (py>=22 || px>=22) continue;
      f32x4 a = acc[of][pf];
      float v0 = fmaxf(a[0]+b0, 0.f), v1 = fmaxf(a[1]+b1, 0.f);
      float v2 = fmaxf(a[2]+b2, 0.f), v3 = fmaxf(a[3]+b3, 0.f);
      if (FINAL){
        size_t base = ((size_t)b*OCHT + og)*484 + py*22 + px;
        outF[base] = v0; outF[base+484] = v1; outF[base+968] = v2; outF[base+1452] = v3;
      } else {
        union { bf16x4 v; uint2 u; } pk;
        pk.v[0] = (__bf16)v0; pk.v[1] = (__bf16)v1; pk.v[2] = (__bf16)v2; pk.v[3] = (__bf16)v3;
        int e = p + 66;
        *reinterpret_cast<uint2*>(Xout + ((size_t)(b*928 + e))*OCHT + og) = pk.u;
      }
    }
  }
}

// weight transpose: cr_w [O][C][25] fp32 -> Wt [O][25][C] bf16
__global__ void wt_make(const float* __restrict__ w, __bf16* __restrict__ wt, int C){
  int o = blockIdx.x;
  for (int c=threadIdx.x; c<C; c+=256){
    const float* src = w + ((size_t)o*C + c)*25;
    float v[25];
    #pragma unroll
    for (int t=0;t<25;t++) v[t] = src[t];
    #pragma unroll
    for (int t=0;t<25;t++) wt[((size_t)o*25 + t)*C + c] = (__bf16)v[t];
  }
}

// ---------------- node feature kernels ----------------
__global__ void k_ent(const float* __restrict__ seq, const int* __restrict__ midx, float* __restrict__ h0){
  int n = blockIdx.x/22, e = blockIdx.x%22;
  int rows[4];
  #pragma unroll
  for (int m=0;m<4;m++) rows[m] = midx[(n*22+e)*4+m];
  for (int d=threadIdx.x; d<512; d+=256){
    float v[4]; float mx = -1e30f;
    #pragma unroll
    for (int m=0;m<4;m++){
      v[m] = seq[((ll)n*1024+rows[m])*512 + d];
      h0[((ll)n*126+22+e*4+m)*532 + d] = v[m];
      mx = fmaxf(mx, v[m]);
    }
    float s = 0.f;
    #pragma unroll
    for (int m=0;m<4;m++) s += expf(v[m]-mx);
    h0[((ll)n*126+e)*532 + d] = mx + logf(s);
  }
}

__global__ void k_link(const float* __restrict__ att, const float* __restrict__ seq,
                       const int* __restrict__ ls_, float* __restrict__ h0){
  int n = blockIdx.x/16, l = blockIdx.x%16;
  int ls = ls_[n*16+l];
  int t = threadIdx.x; int tt = t>>3, lane = t&7;
  __shared__ float part[32][8];
  __shared__ float wv[32];
  float acc = 0.f;
  for (int i=lane; i<384; i+=8){
    int h = i>>5, s = i&31;
    acc += att[((ll)(n*12+h)*1024 + ls+s)*1024 + (ls+tt)];
  }
  part[tt][lane] = acc; __syncthreads();
  if (lane==0){
    float s2=0.f;
    #pragma unroll
    for (int q=0;q<8;q++) s2 += part[tt][q];
    wv[tt] = s2*(1.f/12.f);
  }
  __syncthreads();
  for (int d=t; d<512; d+=256){
    float a2 = 0.f;
    for (int tk=0;tk<32;tk++) a2 += wv[tk]*seq[((ll)n*1024+ls+tk)*512 + d];
    h0[((ll)n*126+110+l)*532 + d] = a2*(1.f/32.f);
  }
}

__global__ void k_tfeat(const float* __restrict__ te, float* __restrict__ h0){
  int idx = blockIdx.x*256 + threadIdx.x;
  if (idx >= 4*126*20) return;
  int t = idx%20; int i = (idx/20)%126; int n = idx/(20*126);
  int ty = (i<22)?0:((i<110)?1:2);
  h0[((ll)n*126+i)*532 + 512 + t] = te[ty*20+t];
}

__global__ void k_ea(const float* __restrict__ att, const int* __restrict__ midx, float* __restrict__ ea){
  int n = blockIdx.x/22, e = blockIdx.x%22;
  int t = threadIdx.x;
  __shared__ float vals[1024];
  __shared__ float red[256];
  int rows[4];
  #pragma unroll
  for (int m=0;m<4;m++) rows[m] = midx[(n*22+e)*4+m];
  float local = 0.f;
  for (int c=t; c<1024; c+=256){
    float acc = 0.f;
    #pragma unroll
    for (int m=0;m<4;m++){
      const float* base = att + ((ll)n*12*1024 + rows[m])*1024 + c;
      for (int h=0;h<12;h++) acc += base[(ll)h*1024*1024];
    }
    acc *= (1.f/48.f);
    vals[c] = acc; local += acc;
  }
  red[t] = local; __syncthreads();
  for (int s=128;s>0;s>>=1){ if (t<s) red[t]+=red[t+s]; __syncthreads(); }
  float denom = red[0] + 1e-5f;
  for (int c=t; c<1024; c+=256) ea[((ll)n*22+e)*1024 + c] = vals[c]/denom;
}

// ---------------- RGCN buildX (emits split bf16, padded) ----------------
__global__ void k_buildX(const float* __restrict__ adj, const float* __restrict__ h,
                         __bf16* __restrict__ Xhi, __bf16* __restrict__ Xlo,
                         int Din, int ldX){
  int n = blockIdx.x/126, i = blockIdx.x%126;
  ll rowoff = (ll)(n*126+i)*ldX;
  for (int d=threadIdx.x; d<Din; d+=256){
    float hh = h[((ll)n*126+i)*Din + d];
    #pragma unroll
    for (int r=0;r<3;r++){
      const float* arow = adj + (r*126+i)*126;
      float acc = 0.f;
      for (int j=0;j<126;j++){
        float a = arow[j];
        if (a != 0.f) acc += a * h[((ll)n*126+j)*Din + d];
      }
      __bf16 hi = (__bf16)acc;
      Xhi[rowoff + r*Din + d] = hi;
      Xlo[rowoff + r*Din + d] = (__bf16)(acc - (float)hi);
    }
    __bf16 hi = (__bf16)hh;
    Xhi[rowoff + 3*Din + d] = hi;
    Xlo[rowoff + 3*Din + d] = (__bf16)(hh - (float)hi);
  }
  for (int k=4*Din+threadIdx.x; k<ldX; k+=256){
    Xhi[rowoff + k] = (__bf16)0.f;
    Xlo[rowoff + k] = (__bf16)0.f;
  }
}

// ---------------- pairwise map / SE / fuse ----------------
__global__ void k_ec(const float* __restrict__ hfin, const float* __restrict__ ectx, float* __restrict__ ec){
  int idx = blockIdx.x*256 + threadIdx.x; // 45056 exact
  int d = idx & 511; int e = (idx>>9)%22; int n = idx/(22*512);
  ec[idx] = hfin[((ll)n*126+e)*512 + d] + ectx[idx];
}

// fmapT bf16 [n][484 px][512 ch]
__global__ void k_fmapT(const float* __restrict__ ec, __bf16* __restrict__ fmapT){
  int idx = blockIdx.x*256 + threadIdx.x; // 991232 exact
  int ch = idx & 511; int p = (idx>>9) % 484; int n = idx/(484*512);
  int i = p/22, j = p%22;
  float v = ec[((ll)n*22+i)*512+ch] * ec[((ll)n*22+j)*512+ch];
  fmapT[idx] = (__bf16)v;
}

__global__ void k_pool(const float* __restrict__ ec, float* __restrict__ pooled){
  int idx = blockIdx.x*256 + threadIdx.x;
  if (idx >= 2048) return;
  int n = idx>>9, c = idx&511;
  float s = 0.f;
  for (int i=0;i<22;i++) s += ec[((ll)n*22+i)*512 + c];
  pooled[idx] = s*s*(1.f/484.f);
}

__global__ void k_cb(const float* __restrict__ pooled,
                     const float* __restrict__ w1, const float* __restrict__ b1,
                     const float* __restrict__ g1, const float* __restrict__ be1,
                     const float* __restrict__ w2, const float* __restrict__ b2,
                     const float* __restrict__ g2, const float* __restrict__ be2,
                     float* __restrict__ cb){
  int n = blockIdx.x; int t = threadIdx.x;
  __shared__ float ps[512], t1[256];
  for (int c=t; c<512; c+=256) ps[c] = pooled[n*512+c];
  __syncthreads();
  {
    float acc = 0.f;
    for (int c=0;c<512;c++) acc += w1[t*512+c]*ps[c];
    float v = g1[t]*(acc+b1[t]) + be1[t];
    t1[t] = fmaxf(v, 0.f);
  }
  __syncthreads();
  for (int o=t; o<512; o+=256){
    float acc = 0.f;
    for (int c=0;c<256;c++) acc += w2[o*256+c]*t1[c];
    cb[n*512+o] = g2[o]*(acc+b2[o]) + be2[o];
  }
}

// fused = fmapT * sigmoid(sb + cb), written channel-interleaved bf16 padded
__global__ void k_fused_b(const __bf16* __restrict__ fmapT, const float* __restrict__ sb,
                          const float* __restrict__ cbv, __bf16* __restrict__ Xint1){
  int n = blockIdx.z; int d8 = blockIdx.y;
  int p = blockIdx.x*256 + threadIdx.x;
  if (p >= 484) return;
  int py = p/22, px = p%22;
  int e = (py+2)*32 + px + 2;
  bf16x8 fm = *reinterpret_cast<const bf16x8*>(fmapT + ((ll)(n*484+p))*512 + d8*8);
  union { bf16x8 v; uint4 u; } pk;
  #pragma unroll
  for (int di=0; di<8; ++di){
    float sv = sb[((ll)n*512 + d8*8 + di)*484 + p] + cbv[n*512 + d8*8 + di];
    float sg = 1.f/(1.f + expf(-sv));
    pk.v[di] = (__bf16)((float)fm[di]*sg);
  }
  *reinterpret_cast<uint4*>(Xint1 + ((size_t)(n*928 + e))*512 + d8*8) = pk.u;
}

// ---------------- launcher ----------------
extern "C" void kernel_launch(void* const* d_in, const int* in_sizes, int n_in,
                              void* d_out, int out_size, void* d_ws, size_t ws_size,
                              hipStream_t stream)
{
  (void)in_sizes; (void)n_in; (void)out_size; (void)ws_size;
  const float* seqout   = (const float*)d_in[0];
  const float* att      = (const float*)d_in[1];
  const float* W_trans  = (const float*)d_in[2];
  const float* b_trans  = (const float*)d_in[3];
  const float* type_emb = (const float*)d_in[4];
  const float* Wrel0    = (const float*)d_in[5];
  const float* Wself0   = (const float*)d_in[6];
  const float* Wrel     = (const float*)d_in[7];
  const float* Wself    = (const float*)d_in[8];
  const float* fs_w1    = (const float*)d_in[9];
  const float* fs_b1    = (const float*)d_in[10];
  const float* fs_g1    = (const float*)d_in[11];
  const float* fs_be1   = (const float*)d_in[12];
  const float* fs_w2    = (const float*)d_in[13];
  const float* fs_b2    = (const float*)d_in[14];
  const float* fs_g2    = (const float*)d_in[15];
  const float* fs_be2   = (const float*)d_in[16];
  const float* fc_w1    = (const float*)d_in[17];
  const float* fc_b1    = (const float*)d_in[18];
  const float* fc_g1    = (const float*)d_in[19];
  const float* fc_be1   = (const float*)d_in[20];
  const float* fc_w2    = (const float*)d_in[21];
  const float* fc_b2    = (const float*)d_in[22];
  const float* fc_g2    = (const float*)d_in[23];
  const float* fc_be2   = (const float*)d_in[24];
  const float* cr_w1    = (const float*)d_in[25];
  const float* cr_b1    = (const float*)d_in[26];
  const float* cr_w2    = (const float*)d_in[27];
  const float* cr_b2    = (const float*)d_in[28];
  const float* cr_w3    = (const float*)d_in[29];
  const float* cr_b3    = (const float*)d_in[30];
  const int*   midx     = (const int*)d_in[31];
  const int*   lstart   = (const int*)d_in[32];
  float* out            = (float*)d_out;

  char* wsb = (char*)d_ws;
  size_t off = 0;
  auto allocB = [&](size_t nbytes)->char*{ char* p = wsb + off; off += (nbytes + 63) & ~(size_t)63; return p; };
  float* adj   = (float*)allocB(3*126*126*4);
  float* seq   = (float*)allocB((size_t)4096*512*4);
  float* h0    = (float*)allocB((size_t)504*532*4);
  float* ea    = (float*)allocB((size_t)88*1024*4);
  float* ectx  = (float*)allocB((size_t)88*512*4);
  float* hA    = (float*)allocB((size_t)504*512*4);
  float* hB    = (float*)allocB((size_t)504*512*4);
  float* ec    = (float*)allocB((size_t)88*512*4);
  float* sb    = (float*)allocB((size_t)4*512*484*4);
  float* pooled= (float*)allocB(2048*4);
  float* cbv   = (float*)allocB(2048*4);
  __bf16* sqh  = (__bf16*)allocB((size_t)4096*768*2);
  __bf16* sql  = (__bf16*)allocB((size_t)4096*768*2);
  __bf16* wth  = (__bf16*)allocB((size_t)512*768*2);
  __bf16* wtl  = (__bf16*)allocB((size_t)512*768*2);
  __bf16* Xhi  = (__bf16*)allocB((size_t)504*2144*2);
  __bf16* Xlo  = (__bf16*)allocB((size_t)504*2144*2);
  __bf16* wch  = (__bf16*)allocB((size_t)512*2144*2);
  __bf16* wcl  = (__bf16*)allocB((size_t)512*2144*2);
  __bf16* fmapT= (__bf16*)allocB((size_t)4*484*512*2);
  __bf16* s1bT = (__bf16*)allocB((size_t)4*484*256*2);
  __bf16* w1b  = (__bf16*)allocB((size_t)256*512*2);
  __bf16* w2b  = (__bf16*)allocB((size_t)512*256*2);
  __bf16* Xint1 = (__bf16*)allocB((size_t)4*928*512*2);
  __bf16* Xint2 = (__bf16*)allocB((size_t)4*928*256*2);
  __bf16* Xint3 = (__bf16*)allocB((size_t)4*928*256*2);
  __bf16* Wt1   = (__bf16*)allocB((size_t)256*25*512*2);
  __bf16* Wt2   = (__bf16*)allocB((size_t)256*25*256*2);
  __bf16* Wt3   = (__bf16*)allocB((size_t)512*25*256*2);

  (void)hipMemsetAsync(Xint1, 0, (size_t)4*928*512*2, stream);
  (void)hipMemsetAsync(Xint2, 0, (size_t)4*928*256*2, stream);
  (void)hipMemsetAsync(Xint3, 0, (size_t)4*928*256*2, stream);

  // constants / weights prep
  k_adj<<<378,128,0,stream>>>(adj);
  wt_make<<<256,256,0,stream>>>(cr_w1, Wt1, 512);
  wt_make<<<256,256,0,stream>>>(cr_w2, Wt2, 256);
  wt_make<<<512,256,0,stream>>>(cr_w3, Wt3, 256);
  k_cast_split<<<12288,256,0,stream>>>(seqout, sqh, sql, (ll)4096*768);
  k_castT_split<<<1536,256,0,stream>>>(W_trans, wth, wtl, 768, 512);
  k_cast_hi<<<512,256,0,stream>>>(fs_w1, w1b, 256*512);
  k_cast_hi<<<512,256,0,stream>>>(fs_w2, w2b, 512*256);

  // seq = seqout @ W_trans + b_trans (split MFMA)
  gemm_mfma<1,0><<<dim3(4,64,1),256,0,stream>>>(sqh, sql, wth, wtl, seq, nullptr,
                                                4096,512,768, 0,0, b_trans,nullptr,nullptr,nullptr);
  // node features
  k_ent <<<88,256,0,stream>>>(seq, midx, h0);
  k_link<<<64,256,0,stream>>>(att, seq, lstart, h0);
  k_tfeat<<<40,256,0,stream>>>(type_emb, h0);
  k_ea  <<<88,256,0,stream>>>(att, midx, ea);
  // e_ctx = ea @ seq (small fp32)
  gemm_ep<false><<<dim3(8,1,4),256,0,stream>>>(ea, seq, ectx, 22,512,1024,
                                               (ll)22*1024, (ll)1024*512, (ll)22*512,
                                               nullptr,nullptr,nullptr,nullptr);
  // RGCN layer 0 (Din=532, Kpad=2144)
  k_wcatT<<<4288,256,0,stream>>>(Wrel0, Wself0, wch, wcl, 532, 2144);
  k_buildX<<<504,256,0,stream>>>(adj, h0, Xhi, Xlo, 532, 2144);
  gemm_mfma<1,1><<<dim3(4,8,1),256,0,stream>>>(Xhi, Xlo, wch, wcl, hA, nullptr,
                                               504,512,2144, 0,0, nullptr,nullptr,nullptr,nullptr);
  // RGCN layers 1..3 (Din=512, K=2048)
  float* hcur = hA; float* hnxt = hB;
  for (int l=0;l<3;l++){
    k_wcatT<<<4096,256,0,stream>>>(Wrel + (ll)l*3*512*512, Wself + (ll)l*512*512, wch, wcl, 512, 2048);
    k_buildX<<<504,256,0,stream>>>(adj, hcur, Xhi, Xlo, 512, 2048);
    gemm_mfma<1,1><<<dim3(4,8,1),256,0,stream>>>(Xhi, Xlo, wch, wcl, hnxt, nullptr,
                                                 504,512,2048, 0,0, nullptr,nullptr,nullptr,nullptr);
    float* t = hcur; hcur = hnxt; hnxt = t;
  }
  // ec = h[:, :22] + e_ctx
  k_ec<<<176,256,0,stream>>>(hcur, ectx, ec);
  // fmapT bf16 [n][px][ch]
  k_fmapT<<<3872,256,0,stream>>>(ec, fmapT);
  // SE spatial branch (MFMA, plain bf16)
  gemm_mfma<0,2><<<dim3(4,4,4),256,0,stream>>>(w1b, nullptr, fmapT, nullptr, nullptr, s1bT,
                                               256,484,512, (ll)484*512, (ll)484*256,
                                               nullptr, fs_b1, fs_g1, fs_be1);
  gemm_mfma<0,3><<<dim3(4,8,4),256,0,stream>>>(w2b, nullptr, s1bT, nullptr, sb, nullptr,
                                               512,484,256, (ll)484*256, (ll)512*484,
                                               nullptr, fs_b2, fs_g2, fs_be2);
  // SE channel branch
  k_pool<<<8,256,0,stream>>>(ec, pooled);
  k_cb<<<4,256,0,stream>>>(pooled, fc_w1, fc_b1, fc_g1, fc_be1,
                           fc_w2, fc_b2, fc_g2, fc_be2, cbv);
  // fused -> interleaved padded bf16
  k_fused_b<<<dim3(2,64,4),256,0,stream>>>(fmapT, sb, cbv, Xint1);
  // conv stack (MFMA)
  conv5_mfma<512,256,false><<<dim3(6,4,4),256,0,stream>>>(Xint1, Wt1, cr_b1, Xint2, nullptr);
  conv5_mfma<256,256,false><<<dim3(6,4,4),256,0,stream>>>(Xint2, Wt2, cr_b2, Xint3, nullptr);
  conv5_mfma<256,512,true ><<<dim3(6,8,4),256,0,stream>>>(Xint3, Wt3, cr_b3, nullptr, out);
}

// Round 6
// 653.036 us; speedup vs baseline: 4.6196x; 1.5213x over previous
//
#include <hip/hip_runtime.h>
#include <hip/hip_bf16.h>
#include <stdint.h>

typedef long long ll;
typedef float f32x4 __attribute__((ext_vector_type(4)));
typedef __bf16 bf16x8 __attribute__((ext_vector_type(8)));
typedef __bf16 bf16x4 __attribute__((ext_vector_type(4)));

// ---------------- adjacency is applied in closed form (k_buildX_s) ----------------

// ---------------- casts ----------------
__global__ void k_cast_split(const float* __restrict__ in, __bf16* __restrict__ hi,
                             __bf16* __restrict__ lo, ll n){
  ll idx = (ll)blockIdx.x*256 + threadIdx.x;
  if (idx >= n) return;
  float x = in[idx];
  __bf16 h = (__bf16)x;
  hi[idx] = h; lo[idx] = (__bf16)(x - (float)h);
}
__global__ void k_cast_hi(const float* __restrict__ in, __bf16* __restrict__ hi, ll n){
  ll idx = (ll)blockIdx.x*256 + threadIdx.x;
  if (idx >= n) return;
  hi[idx] = (__bf16)in[idx];
}
// in [R][C] -> out [C][R] (split) -- used for W_trans (768x512 -> 512x768)
__global__ void k_castT_split(const float* __restrict__ in, __bf16* __restrict__ hi,
                              __bf16* __restrict__ lo, int R, int C){
  ll idx = (ll)blockIdx.x*256 + threadIdx.x;
  if (idx >= (ll)R*C) return;
  int r = (int)(idx % R); int c = (int)(idx / R);
  float x = in[(ll)r*C + c];
  __bf16 h = (__bf16)x;
  hi[idx] = h; lo[idx] = (__bf16)(x - (float)h);
}

// WcatT via coalesced tiled transpose. Virtual input V[k][o]: k<3*Din from Wrel,
// k<4*Din from Wself, else 0. Output [o][Kpad] split bf16. grid (Kpad/32, 16, L), block (32,8).
__global__ void k_wcatT2(const float* __restrict__ Wrel, const float* __restrict__ Wself,
                         __bf16* __restrict__ hi, __bf16* __restrict__ lo,
                         int Din, int Kpad){
  __shared__ float t[32][33];
  int l = blockIdx.z;
  const float* wr = Wrel + (ll)l*3*Din*512;
  const float* ws2 = Wself + (ll)l*Din*512;
  __bf16* hb = hi + (ll)l*512*Kpad;
  __bf16* lb = lo + (ll)l*512*Kpad;
  int k0 = blockIdx.x*32, o0 = blockIdx.y*32;
  int tx = threadIdx.x, ty = threadIdx.y;
  for (int j=ty; j<32; j+=8){
    int k = k0 + j; float v = 0.f;
    if (k < 3*Din) v = wr[(ll)k*512 + o0+tx];
    else if (k < 4*Din) v = ws2[(ll)(k-3*Din)*512 + o0+tx];
    t[j][tx] = v;
  }
  __syncthreads();
  for (int j=ty; j<32; j+=8){
    float x = t[tx][j];
    __bf16 h = (__bf16)x;
    hb[(ll)(o0+j)*Kpad + k0+tx] = h;
    lb[(ll)(o0+j)*Kpad + k0+tx] = (__bf16)(x - (float)h);
  }
}

// seqT: seq [n][1024][512] fp32 -> [n][512][1024] split bf16. grid (32,16,4), block (32,8)
__global__ void k_seqT(const float* __restrict__ seq, __bf16* __restrict__ hi,
                       __bf16* __restrict__ lo){
  __shared__ float t[32][33];
  int n = blockIdx.z;
  int r0 = blockIdx.x*32, c0 = blockIdx.y*32;
  int tx = threadIdx.x, ty = threadIdx.y;
  for (int j=ty; j<32; j+=8)
    t[j][tx] = seq[((ll)n*1024 + r0+j)*512 + c0+tx];
  __syncthreads();
  for (int j=ty; j<32; j+=8){
    float x = t[tx][j];
    __bf16 h = (__bf16)x;
    ll o = ((ll)n*512 + c0+j)*1024 + r0+tx;
    hi[o] = h; lo[o] = (__bf16)(x - (float)h);
  }
}

// ---------------- MFMA GEMM: A [M][K] bf16(hi/lo), B^T [N][K] bf16(hi/lo) ----------------
// tile: 64(M) x BN(N), K-step 32. 4 waves = 2(M)x2(N); wave = 32M x (BN/2)N.
// MODE 0: Cf[M][N] = acc + (biasN?biasN:0)    (seq, ectx)
// MODE 1: Cf[M][N] = relu(acc)                (rgcn)
// MODE 2: Cb^T[N][M] = relu((acc+biasM)*g+be) bf16 (se1)
// MODE 3: Cf[M][N] = (acc+biasM)*g+be         (se2)
template<int SPLIT, int MODE, int BN>
__global__ __launch_bounds__(256) void gemm_mfma(
    const __bf16* __restrict__ Ahi, const __bf16* __restrict__ Alo,
    const __bf16* __restrict__ Bhi, const __bf16* __restrict__ Blo,
    float* __restrict__ Cf, __bf16* __restrict__ Cb,
    int M, int N, int K, ll sA, ll sB, ll sC,
    const float* __restrict__ biasN, const float* __restrict__ biasM,
    const float* __restrict__ gM, const float* __restrict__ beM)
{
  constexpr int BS = BN*64;           // B tile bytes
  constexpr int NF = BN/32;           // N frags per wave
  __shared__ bf16x8 lds8[((SPLIT?2:1)*(4096+BS))/16];
  char* lds = (char*)lds8;
  char* asH = lds;
  char* bsH = lds + 4096;
  char* asL = lds + 4096 + BS;
  char* bsL = lds + 8192 + BS;

  int b = blockIdx.z;
  Ahi += sA*b; Bhi += sB*b;
  if (SPLIT){ Alo += sA*b; Blo += sB*b; }

  const int tid = threadIdx.x;
  const int l15 = tid & 15, lg = (tid&63)>>4, lg16 = ((tid&63)>>4)*16;
  const int w = tid >> 6;
  const int wave_m0 = (w>>1)*32, wave_n0 = (w&1)*(BN/2);
  const int m0 = blockIdx.y*64, n0 = blockIdx.x*BN;

  const int sa_row = tid>>2, sa_c8 = tid&3;
  const int sa_byte = sa_row*64 + ((sa_c8*16) ^ (((sa_row>>1)&3)<<4));
  const int gmA = m0 + sa_row;

  int baseA[2], baseB[NF];
  #pragma unroll
  for (int mf=0; mf<2; ++mf){
    int r = wave_m0 + mf*16 + l15;
    baseA[mf] = r*64 + (lg16 ^ (((r>>1)&3)<<4));
  }
  #pragma unroll
  for (int nf=0; nf<NF; ++nf){
    int r = wave_n0 + nf*16 + l15;
    baseB[nf] = r*64 + (lg16 ^ (((r>>1)&3)<<4));
  }

  f32x4 acc[2][NF] = {};

  for (int k0=0; k0<K; k0+=32){
    __syncthreads();
    {
      bf16x8 v = {};
      if (gmA < M) v = *reinterpret_cast<const bf16x8*>(Ahi + (ll)gmA*K + k0 + sa_c8*8);
      *reinterpret_cast<bf16x8*>(asH + sa_byte) = v;
      if (SPLIT){
        bf16x8 vl = {};
        if (gmA < M) vl = *reinterpret_cast<const bf16x8*>(Alo + (ll)gmA*K + k0 + sa_c8*8);
        *reinterpret_cast<bf16x8*>(asL + sa_byte) = vl;
      }
    }
    #pragma unroll
    for (int i=0;i<BN/64;i++){
      int idx = tid + i*256;
      int row = idx>>2, c8 = idx&3;
      int gn = n0 + row;
      int byte = row*64 + ((c8*16) ^ (((row>>1)&3)<<4));
      bf16x8 v = {};
      if (gn < N) v = *reinterpret_cast<const bf16x8*>(Bhi + (ll)gn*K + k0 + c8*8);
      *reinterpret_cast<bf16x8*>(bsH + byte) = v;
      if (SPLIT){
        bf16x8 vl = {};
        if (gn < N) vl = *reinterpret_cast<const bf16x8*>(Blo + (ll)gn*K + k0 + c8*8);
        *reinterpret_cast<bf16x8*>(bsL + byte) = vl;
      }
    }
    __syncthreads();
    bf16x8 aH[2], bH[NF];
    #pragma unroll
    for (int mf=0; mf<2; ++mf) aH[mf] = *reinterpret_cast<const bf16x8*>(asH + baseA[mf]);
    #pragma unroll
    for (int nf=0; nf<NF; ++nf) bH[nf] = *reinterpret_cast<const bf16x8*>(bsH + baseB[nf]);
    if (SPLIT){
      bf16x8 aL[2], bL[NF];
      #pragma unroll
      for (int mf=0; mf<2; ++mf) aL[mf] = *reinterpret_cast<const bf16x8*>(asL + baseA[mf]);
      #pragma unroll
      for (int nf=0; nf<NF; ++nf) bL[nf] = *reinterpret_cast<const bf16x8*>(bsL + baseB[nf]);
      #pragma unroll
      for (int mf=0; mf<2; ++mf)
        #pragma unroll
        for (int nf=0; nf<NF; ++nf){
          acc[mf][nf] = __builtin_amdgcn_mfma_f32_16x16x32_bf16(aH[mf], bH[nf], acc[mf][nf], 0,0,0);
          acc[mf][nf] = __builtin_amdgcn_mfma_f32_16x16x32_bf16(aH[mf], bL[nf], acc[mf][nf], 0,0,0);
          acc[mf][nf] = __builtin_amdgcn_mfma_f32_16x16x32_bf16(aL[mf], bH[nf], acc[mf][nf], 0,0,0);
        }
    } else {
      #pragma unroll
      for (int mf=0; mf<2; ++mf)
        #pragma unroll
        for (int nf=0; nf<NF; ++nf)
          acc[mf][nf] = __builtin_amdgcn_mfma_f32_16x16x32_bf16(aH[mf], bH[nf], acc[mf][nf], 0,0,0);
    }
  }

  if (MODE==0 || MODE==1){
    float* C = Cf + sC*b;
    #pragma unroll
    for (int mf=0; mf<2; ++mf){
      int gmb = m0 + wave_m0 + mf*16 + lg*4;
      #pragma unroll
      for (int nf=0; nf<NF; ++nf){
        int gn = n0 + wave_n0 + nf*16 + l15;
        if (gn >= N) continue;
        float bn_ = (MODE==0 && biasN) ? biasN[gn] : 0.f;
        f32x4 a = acc[mf][nf];
        #pragma unroll
        for (int r=0;r<4;r++){
          int gm = gmb + r;
          if (gm < M){
            float v = a[r] + bn_;
            if (MODE==1) v = fmaxf(v, 0.f);
            C[(ll)gm*N + gn] = v;
          }
        }
      }
    }
  } else if (MODE==2){
    __bf16* C = Cb + sC*b;
    #pragma unroll
    for (int mf=0; mf<2; ++mf){
      int gmb = m0 + wave_m0 + mf*16 + lg*4;
      float b0=biasM[gmb], b1=biasM[gmb+1], b2=biasM[gmb+2], b3=biasM[gmb+3];
      float g0=gM[gmb], g1=gM[gmb+1], g2=gM[gmb+2], g3=gM[gmb+3];
      float e0=beM[gmb], e1=beM[gmb+1], e2=beM[gmb+2], e3=beM[gmb+3];
      #pragma unroll
      for (int nf=0; nf<NF; ++nf){
        int gn = n0 + wave_n0 + nf*16 + l15;
        if (gn >= N) continue;
        f32x4 a = acc[mf][nf];
        union { bf16x4 v; uint2 u; } pk;
        pk.v[0] = (__bf16)fmaxf((a[0]+b0)*g0+e0, 0.f);
        pk.v[1] = (__bf16)fmaxf((a[1]+b1)*g1+e1, 0.f);
        pk.v[2] = (__bf16)fmaxf((a[2]+b2)*g2+e2, 0.f);
        pk.v[3] = (__bf16)fmaxf((a[3]+b3)*g3+e3, 0.f);
        *reinterpret_cast<uint2*>(C + (ll)gn*M + gmb) = pk.u;
      }
    }
  } else { // MODE 3
    float* C = Cf + sC*b;
    #pragma unroll
    for (int mf=0; mf<2; ++mf){
      int gmb = m0 + wave_m0 + mf*16 + lg*4;
      float b0=biasM[gmb], b1=biasM[gmb+1], b2=biasM[gmb+2], b3=biasM[gmb+3];
      float g0=gM[gmb], g1=gM[gmb+1], g2=gM[gmb+2], g3=gM[gmb+3];
      float e0=beM[gmb], e1=beM[gmb+1], e2=beM[gmb+2], e3=beM[gmb+3];
      #pragma unroll
      for (int nf=0; nf<NF; ++nf){
        int gn = n0 + wave_n0 + nf*16 + l15;
        if (gn >= N) continue;
        f32x4 a = acc[mf][nf];
        C[(ll)(gmb+0)*N + gn] = (a[0]+b0)*g0+e0;
        C[(ll)(gmb+1)*N + gn] = (a[1]+b1)*g1+e1;
        C[(ll)(gmb+2)*N + gn] = (a[2]+b2)*g2+e2;
        C[(ll)(gmb+3)*N + gn] = (a[3]+b3)*g3+e3;
      }
    }
  }
}

// ---------------- MFMA bf16 5x5 conv (verified r3 structure) ----------------
template<int CIN, int OCHT, bool FINAL>
__global__ __launch_bounds__(256) void conv5_mfma(
    const __bf16* __restrict__ Xg, const __bf16* __restrict__ Wt,
    const float* __restrict__ bias, __bf16* __restrict__ Xout,
    float* __restrict__ outF)
{
  __shared__ bf16x8 Xs8[272*32/8];
  __shared__ bf16x8 Ws8[5*64*32/8];
  char* xs = (char*)Xs8;
  char* wsm = (char*)Ws8;

  const int tid = threadIdx.x;
  const int l = tid & 63;
  const int l15 = l & 15, lg = l >> 4, lg16 = (l>>4)*16;
  const int w = tid >> 6;
  const int wave_o0 = (w>>1)*32;
  const int wave_p0 = (w&1)*64;
  const int b = blockIdx.z;
  const int p0 = blockIdx.x*128;
  const int o0 = blockIdx.y*64;

  int orow0 = wave_o0 + l15;
  int orow1 = wave_o0 + 16 + l15;
  int baseA0 = orow0*64 + (lg16 ^ (((orow0>>1)&3)<<4));
  int baseA1 = orow1*64 + (lg16 ^ (((orow1>>1)&3)<<4));
  int pl[4];
  #pragma unroll
  for (int pf=0; pf<4; ++pf) pl[pf] = wave_p0 + pf*16 + l15;

  f32x4 acc[2][4] = {};

  const int NCB = CIN/32;
  for (int cblk=0; cblk<NCB; ++cblk){
    __syncthreads();
    #pragma unroll
    for (int i=0;i<5;i++){
      int idx = tid + i*256;
      if (idx < 1088){
        int e = idx>>2, c8 = idx&3;
        const __bf16* g = Xg + ((size_t)(b*928 + p0 + e))*CIN + cblk*32 + c8*8;
        bf16x8 v = *reinterpret_cast<const bf16x8*>(g);
        int byte = e*64 + ((c8*16) ^ (((e>>1)&3)<<4));
        *reinterpret_cast<bf16x8*>(xs + byte) = v;
      }
    }
    for (int g5=0; g5<5; ++g5){
      if (g5>0) __syncthreads();
      #pragma unroll
      for (int i=0;i<5;i++){
        int idx = tid + i*256;
        int tapL = idx>>8, r = idx&255;
        int o = r>>2, c8 = r&3;
        const __bf16* g = Wt + ((size_t)(o0+o)*25 + (g5*5+tapL))*CIN + cblk*32 + c8*8;
        bf16x8 v = *reinterpret_cast<const bf16x8*>(g);
        int byte = tapL*4096 + o*64 + ((c8*16) ^ (((o>>1)&3)<<4));
        *reinterpret_cast<bf16x8*>(wsm + byte) = v;
      }
      __syncthreads();
      #pragma unroll
      for (int tapL=0; tapL<5; ++tapL){
        bf16x8 a0 = *reinterpret_cast<const bf16x8*>(wsm + tapL*4096 + baseA0);
        bf16x8 a1 = *reinterpret_cast<const bf16x8*>(wsm + tapL*4096 + baseA1);
        int koff = g5*32 + tapL;
        #pragma unroll
        for (int pf=0; pf<4; ++pf){
          int e = pl[pf] + koff;
          bf16x8 bv = *reinterpret_cast<const bf16x8*>(xs + e*64 + (lg16 ^ (((e>>1)&3)<<4)));
          acc[0][pf] = __builtin_amdgcn_mfma_f32_16x16x32_bf16(a0, bv, acc[0][pf], 0,0,0);
          acc[1][pf] = __builtin_amdgcn_mfma_f32_16x16x32_bf16(a1, bv, acc[1][pf], 0,0,0);
        }
      }
    }
  }

  #pragma unroll
  for (int of=0; of<2; ++of){
    int og = o0 + wave_o0 + of*16 + lg*4;
    float b0 = bias[og], b1 = bias[og+1], b2 = bias[og+2], b3 = bias[og+3];
    #pragma unroll
    for (int pf=0; pf<4; ++pf){
      int p = p0 + pl[pf];
      int py = p>>5, px = p&31;
      if (py>=22 || px>=22) continue;
      f32x4 a = acc[of][pf];
      float v0 = fmaxf(a[0]+b0, 0.f), v1 = fmaxf(a[1]+b1, 0.f);
      float v2 = fmaxf(a[2]+b2, 0.f), v3 = fmaxf(a[3]+b3, 0.f);
      if (FINAL){
        size_t base = ((size_t)b*OCHT + og)*484 + py*22 + px;
        outF[base] = v0; outF[base+484] = v1; outF[base+968] = v2; outF[base+1452] = v3;
      } else {
        union { bf16x4 v; uint2 u; } pk;
        pk.v[0] = (__bf16)v0; pk.v[1] = (__bf16)v1; pk.v[2] = (__bf16)v2; pk.v[3] = (__bf16)v3;
        int e = p + 66;
        *reinterpret_cast<uint2*>(Xout + ((size_t)(b*928 + e))*OCHT + og) = pk.u;
      }
    }
  }
}

// weight transpose: cr_w [O][C][25] fp32 -> Wt [O][25][C] bf16
__global__ void wt_make(const float* __restrict__ w, __bf16* __restrict__ wt, int C){
  int o = blockIdx.x;
  for (int c=threadIdx.x; c<C; c+=256){
    const float* src = w + ((size_t)o*C + c)*25;
    float v[25];
    #pragma unroll
    for (int t=0;t<25;t++) v[t] = src[t];
    #pragma unroll
    for (int t=0;t<25;t++) wt[((size_t)o*25 + t)*C + c] = (__bf16)v[t];
  }
}

// ---------------- node feature kernels ----------------
__global__ void k_ent(const float* __restrict__ seq, const int* __restrict__ midx, float* __restrict__ h0){
  int n = blockIdx.x/22, e = blockIdx.x%22;
  int rows[4];
  #pragma unroll
  for (int m=0;m<4;m++) rows[m] = midx[(n*22+e)*4+m];
  for (int d=threadIdx.x; d<512; d+=256){
    float v[4]; float mx = -1e30f;
    #pragma unroll
    for (int m=0;m<4;m++){
      v[m] = seq[((ll)n*1024+rows[m])*512 + d];
      h0[((ll)n*126+22+e*4+m)*532 + d] = v[m];
      mx = fmaxf(mx, v[m]);
    }
    float s = 0.f;
    #pragma unroll
    for (int m=0;m<4;m++) s += expf(v[m]-mx);
    h0[((ll)n*126+e)*532 + d] = mx + logf(s);
  }
}

__global__ void k_link(const float* __restrict__ att, const float* __restrict__ seq,
                       const int* __restrict__ ls_, float* __restrict__ h0){
  int n = blockIdx.x/16, l = blockIdx.x%16;
  int ls = ls_[n*16+l];
  int t = threadIdx.x; int tt = t>>3, lane = t&7;
  __shared__ float part[32][8];
  __shared__ float wv[32];
  float acc = 0.f;
  for (int i=lane; i<384; i+=8){
    int h = i>>5, s = i&31;
    acc += att[((ll)(n*12+h)*1024 + ls+s)*1024 + (ls+tt)];
  }
  part[tt][lane] = acc; __syncthreads();
  if (lane==0){
    float s2=0.f;
    #pragma unroll
    for (int q=0;q<8;q++) s2 += part[tt][q];
    wv[tt] = s2*(1.f/12.f);
  }
  __syncthreads();
  for (int d=t; d<512; d+=256){
    float a2 = 0.f;
    for (int tk=0;tk<32;tk++) a2 += wv[tk]*seq[((ll)n*1024+ls+tk)*512 + d];
    h0[((ll)n*126+110+l)*532 + d] = a2*(1.f/32.f);
  }
}

__global__ void k_tfeat(const float* __restrict__ te, float* __restrict__ h0){
  int idx = blockIdx.x*256 + threadIdx.x;
  if (idx >= 4*126*20) return;
  int t = idx%20; int i = (idx/20)%126; int n = idx/(20*126);
  int ty = (i<22)?0:((i<110)?1:2);
  h0[((ll)n*126+i)*532 + 512 + t] = te[ty*20+t];
}

// ea stage 1: per (n,e,h) partial over 4 mentions. grid 4*22*12
__global__ void k_ea1(const float* __restrict__ att, const int* __restrict__ midx,
                      float* __restrict__ eap){
  int b = blockIdx.x;
  int h = b%12; int e = (b/12)%22; int n = b/(12*22);
  int rows[4];
  #pragma unroll
  for (int m=0;m<4;m++) rows[m] = midx[(n*22+e)*4+m];
  const float* base = att + (ll)(n*12+h)*1024*1024;
  for (int c=threadIdx.x; c<1024; c+=256){
    float acc = 0.f;
    #pragma unroll
    for (int m=0;m<4;m++) acc += base[(ll)rows[m]*1024 + c];
    eap[(ll)b*1024 + c] = acc;
  }
}
// ea stage 2: reduce heads + normalize. grid 88
__global__ void k_ea2(const float* __restrict__ eap, float* __restrict__ ea){
  int b = blockIdx.x; int t = threadIdx.x;
  __shared__ float vals[1024];
  __shared__ float red[256];
  float local = 0.f;
  for (int c=t; c<1024; c+=256){
    float s = 0.f;
    #pragma unroll
    for (int h=0;h<12;h++) s += eap[(ll)(b*12+h)*1024 + c];
    s *= (1.f/48.f);
    vals[c] = s; local += s;
  }
  red[t] = local; __syncthreads();
  for (int s=128;s>0;s>>=1){ if (t<s) red[t]+=red[t+s]; __syncthreads(); }
  float denom = red[0] + 1e-5f;
  for (int c=t; c<1024; c+=256) ea[(ll)b*1024 + c] = vals[c]/denom;
}

// ---------------- sparse RGCN buildX (closed-form adjacency) ----------------
// nodes: 0..21 entities, 22..109 mentions, 110..125 links.
__global__ void k_buildX_s(const float* __restrict__ h,
                           __bf16* __restrict__ Xhi, __bf16* __restrict__ Xlo,
                           int Din, int ldX){
  int n = blockIdx.x/126, i = blockIdx.x%126;
  const float* hb = h + (ll)n*126*Din;
  ll rowoff = (ll)(n*126+i)*ldX;
  const float inv1 = 1.f/(1.f+1e-5f), inv3 = 1.f/(3.f+1e-5f), inv4 = 1.f/(4.f+1e-5f);
  for (int d=threadIdx.x; d<Din; d+=256){
    float m0v=0.f, m1v=0.f, m2v=0.f;
    if (i < 22){
      int base = 22 + i*4;
      float s = hb[(ll)(base+0)*Din+d] + hb[(ll)(base+1)*Din+d]
              + hb[(ll)(base+2)*Din+d] + hb[(ll)(base+3)*Din+d];
      m0v = s * inv4;
    } else if (i < 110){
      int em = i-22, e = em>>2, base = 22+(e<<2);
      m0v = hb[(ll)e*Din+d] * inv1;
      float s1 = 0.f;
      #pragma unroll
      for (int m2=0;m2<4;m2++) if (base+m2 != i) s1 += hb[(ll)(base+m2)*Din+d];
      m1v = s1 * inv3;
      m2v = hb[(ll)(110+(em&15))*Din+d] * inv1;
    } else {
      int li0 = i-110;
      int cnt = (li0<8)?6:5;
      float s = 0.f;
      for (int t2=0;t2<cnt;t2++) s += hb[(ll)(22+li0+16*t2)*Din+d];
      m2v = s / ((float)cnt + 1e-5f);
    }
    float hh = hb[(ll)i*Din+d];
    float v4[4] = {m0v, m1v, m2v, hh};
    #pragma unroll
    for (int r=0;r<4;r++){
      __bf16 hi = (__bf16)v4[r];
      Xhi[rowoff + r*Din + d] = hi;
      Xlo[rowoff + r*Din + d] = (__bf16)(v4[r] - (float)hi);
    }
  }
  for (int k=4*Din+threadIdx.x; k<ldX; k+=256){
    Xhi[rowoff + k] = (__bf16)0.f;
    Xlo[rowoff + k] = (__bf16)0.f;
  }
}

// ---------------- pairwise map / SE / fuse ----------------
__global__ void k_ec(const float* __restrict__ hfin, const float* __restrict__ ectx, float* __restrict__ ec){
  int idx = blockIdx.x*256 + threadIdx.x; // 45056 exact
  int d = idx & 511; int e = (idx>>9)%22; int n = idx/(22*512);
  ec[idx] = hfin[((ll)n*126+e)*512 + d] + ectx[idx];
}

// fmapT bf16 [n][484 px][512 ch]
__global__ void k_fmapT(const float* __restrict__ ec, __bf16* __restrict__ fmapT){
  int idx = blockIdx.x*256 + threadIdx.x; // 991232 exact
  int ch = idx & 511; int p = (idx>>9) % 484; int n = idx/(484*512);
  int i = p/22, j = p%22;
  float v = ec[((ll)n*22+i)*512+ch] * ec[((ll)n*22+j)*512+ch];
  fmapT[idx] = (__bf16)v;
}

__global__ void k_pool(const float* __restrict__ ec, float* __restrict__ pooled){
  int idx = blockIdx.x*256 + threadIdx.x;
  if (idx >= 2048) return;
  int n = idx>>9, c = idx&511;
  float s = 0.f;
  for (int i=0;i<22;i++) s += ec[((ll)n*22+i)*512 + c];
  pooled[idx] = s*s*(1.f/484.f);
}

__global__ void k_cb(const float* __restrict__ pooled,
                     const float* __restrict__ w1, const float* __restrict__ b1,
                     const float* __restrict__ g1, const float* __restrict__ be1,
                     const float* __restrict__ w2, const float* __restrict__ b2,
                     const float* __restrict__ g2, const float* __restrict__ be2,
                     float* __restrict__ cb){
  int n = blockIdx.x; int t = threadIdx.x;
  __shared__ float ps[512], t1[256];
  for (int c=t; c<512; c+=256) ps[c] = pooled[n*512+c];
  __syncthreads();
  {
    float acc = 0.f;
    for (int c=0;c<512;c++) acc += w1[t*512+c]*ps[c];
    float v = g1[t]*(acc+b1[t]) + be1[t];
    t1[t] = fmaxf(v, 0.f);
  }
  __syncthreads();
  for (int o=t; o<512; o+=256){
    float acc = 0.f;
    for (int c=0;c<256;c++) acc += w2[o*256+c]*t1[c];
    cb[n*512+o] = g2[o]*(acc+b2[o]) + be2[o];
  }
}

// fused = fmapT * sigmoid(sb + cb), written channel-interleaved bf16 padded
__global__ void k_fused_b(const __bf16* __restrict__ fmapT, const float* __restrict__ sb,
                          const float* __restrict__ cbv, __bf16* __restrict__ Xint1){
  int n = blockIdx.z; int d8 = blockIdx.y;
  int p = blockIdx.x*256 + threadIdx.x;
  if (p >= 484) return;
  int py = p/22, px = p%22;
  int e = (py+2)*32 + px + 2;
  bf16x8 fm = *reinterpret_cast<const bf16x8*>(fmapT + ((ll)(n*484+p))*512 + d8*8);
  union { bf16x8 v; uint4 u; } pk;
  #pragma unroll
  for (int di=0; di<8; ++di){
    float sv = sb[((ll)n*512 + d8*8 + di)*484 + p] + cbv[n*512 + d8*8 + di];
    float sg = 1.f/(1.f + expf(-sv));
    pk.v[di] = (__bf16)((float)fm[di]*sg);
  }
  *reinterpret_cast<uint4*>(Xint1 + ((size_t)(n*928 + e))*512 + d8*8) = pk.u;
}

// ---------------- launcher ----------------
extern "C" void kernel_launch(void* const* d_in, const int* in_sizes, int n_in,
                              void* d_out, int out_size, void* d_ws, size_t ws_size,
                              hipStream_t stream)
{
  (void)in_sizes; (void)n_in; (void)out_size; (void)ws_size;
  const float* seqout   = (const float*)d_in[0];
  const float* att      = (const float*)d_in[1];
  const float* W_trans  = (const float*)d_in[2];
  const float* b_trans  = (const float*)d_in[3];
  const float* type_emb = (const float*)d_in[4];
  const float* Wrel0    = (const float*)d_in[5];
  const float* Wself0   = (const float*)d_in[6];
  const float* Wrel     = (const float*)d_in[7];
  const float* Wself    = (const float*)d_in[8];
  const float* fs_w1    = (const float*)d_in[9];
  const float* fs_b1    = (const float*)d_in[10];
  const float* fs_g1    = (const float*)d_in[11];
  const float* fs_be1   = (const float*)d_in[12];
  const float* fs_w2    = (const float*)d_in[13];
  const float* fs_b2    = (const float*)d_in[14];
  const float* fs_g2    = (const float*)d_in[15];
  const float* fs_be2   = (const float*)d_in[16];
  const float* fc_w1    = (const float*)d_in[17];
  const float* fc_b1    = (const float*)d_in[18];
  const float* fc_g1    = (const float*)d_in[19];
  const float* fc_be1   = (const float*)d_in[20];
  const float* fc_w2    = (const float*)d_in[21];
  const float* fc_b2    = (const float*)d_in[22];
  const float* fc_g2    = (const float*)d_in[23];
  const float* fc_be2   = (const float*)d_in[24];
  const float* cr_w1    = (const float*)d_in[25];
  const float* cr_b1    = (const float*)d_in[26];
  const float* cr_w2    = (const float*)d_in[27];
  const float* cr_b2    = (const float*)d_in[28];
  const float* cr_w3    = (const float*)d_in[29];
  const float* cr_b3    = (const float*)d_in[30];
  const int*   midx     = (const int*)d_in[31];
  const int*   lstart   = (const int*)d_in[32];
  float* out            = (float*)d_out;

  char* wsb = (char*)d_ws;
  size_t off = 0;
  auto allocB = [&](size_t nbytes)->char*{ char* p = wsb + off; off += (nbytes + 63) & ~(size_t)63; return p; };
  float* seq   = (float*)allocB((size_t)4096*512*4);
  float* h0    = (float*)allocB((size_t)504*532*4);
  float* eap   = (float*)allocB((size_t)4224*1024*4);
  float* ea    = (float*)allocB((size_t)88*1024*4);
  float* ectx  = (float*)allocB((size_t)88*512*4);
  float* hA    = (float*)allocB((size_t)504*512*4);
  float* hB    = (float*)allocB((size_t)504*512*4);
  float* ec    = (float*)allocB((size_t)88*512*4);
  float* sb    = (float*)allocB((size_t)4*512*484*4);
  float* pooled= (float*)allocB(2048*4);
  float* cbv   = (float*)allocB(2048*4);
  __bf16* sqh  = (__bf16*)allocB((size_t)4096*768*2);
  __bf16* sql  = (__bf16*)allocB((size_t)4096*768*2);
  __bf16* wth  = (__bf16*)allocB((size_t)512*768*2);
  __bf16* wtl  = (__bf16*)allocB((size_t)512*768*2);
  __bf16* sqTh = (__bf16*)allocB((size_t)4*512*1024*2);
  __bf16* sqTl = (__bf16*)allocB((size_t)4*512*1024*2);
  __bf16* eah  = (__bf16*)allocB((size_t)88*1024*2);
  __bf16* eal  = (__bf16*)allocB((size_t)88*1024*2);
  __bf16* Xhi  = (__bf16*)allocB((size_t)504*2144*2);
  __bf16* Xlo  = (__bf16*)allocB((size_t)504*2144*2);
  __bf16* wc0h = (__bf16*)allocB((size_t)512*2144*2);
  __bf16* wc0l = (__bf16*)allocB((size_t)512*2144*2);
  __bf16* wc13h= (__bf16*)allocB((size_t)3*512*2048*2);
  __bf16* wc13l= (__bf16*)allocB((size_t)3*512*2048*2);
  __bf16* fmapT= (__bf16*)allocB((size_t)4*484*512*2);
  __bf16* s1bT = (__bf16*)allocB((size_t)4*484*256*2);
  __bf16* w1b  = (__bf16*)allocB((size_t)256*512*2);
  __bf16* w2b  = (__bf16*)allocB((size_t)512*256*2);
  __bf16* Xint1 = (__bf16*)allocB((size_t)4*928*512*2);
  __bf16* Xint2 = (__bf16*)allocB((size_t)4*928*256*2);
  __bf16* Xint3 = (__bf16*)allocB((size_t)4*928*256*2);
  __bf16* Wt1   = (__bf16*)allocB((size_t)256*25*512*2);
  __bf16* Wt2   = (__bf16*)allocB((size_t)256*25*256*2);
  __bf16* Wt3   = (__bf16*)allocB((size_t)512*25*256*2);

  (void)hipMemsetAsync(Xint1, 0, (size_t)4*928*512*2, stream);
  (void)hipMemsetAsync(Xint2, 0, (size_t)4*928*256*2, stream);
  (void)hipMemsetAsync(Xint3, 0, (size_t)4*928*256*2, stream);

  // weights prep (off critical path data-wise, but same stream)
  wt_make<<<256,256,0,stream>>>(cr_w1, Wt1, 512);
  wt_make<<<256,256,0,stream>>>(cr_w2, Wt2, 256);
  wt_make<<<512,256,0,stream>>>(cr_w3, Wt3, 256);
  k_cast_split<<<12288,256,0,stream>>>(seqout, sqh, sql, (ll)4096*768);
  k_castT_split<<<1536,256,0,stream>>>(W_trans, wth, wtl, 768, 512);
  k_cast_hi<<<512,256,0,stream>>>(fs_w1, w1b, 256*512);
  k_cast_hi<<<512,256,0,stream>>>(fs_w2, w2b, 512*256);
  k_wcatT2<<<dim3(67,16,1),dim3(32,8),0,stream>>>(Wrel0, Wself0, wc0h, wc0l, 532, 2144);
  k_wcatT2<<<dim3(64,16,3),dim3(32,8),0,stream>>>(Wrel, Wself, wc13h, wc13l, 512, 2048);

  // seq = seqout @ W_trans + b_trans (split MFMA)
  gemm_mfma<1,0,128><<<dim3(4,64,1),256,0,stream>>>(sqh, sql, wth, wtl, seq, nullptr,
                                                    4096,512,768, 0,0,0, b_trans,nullptr,nullptr,nullptr);
  // node features
  k_ent <<<88,256,0,stream>>>(seq, midx, h0);
  k_link<<<64,256,0,stream>>>(att, seq, lstart, h0);
  k_tfeat<<<40,256,0,stream>>>(type_emb, h0);
  k_ea1<<<1056,256,0,stream>>>(att, midx, eap);
  k_ea2<<<88,256,0,stream>>>(eap, ea);
  // e_ctx = ea @ seq via MFMA: seqT + ea split
  k_seqT<<<dim3(32,16,4),dim3(32,8),0,stream>>>(seq, sqTh, sqTl);
  k_cast_split<<<352,256,0,stream>>>(ea, eah, eal, (ll)88*1024);
  gemm_mfma<1,0,64><<<dim3(8,1,4),256,0,stream>>>(eah, eal, sqTh, sqTl, ectx, nullptr,
                                                  22,512,1024, (ll)22*1024, (ll)512*1024, (ll)22*512,
                                                  nullptr,nullptr,nullptr,nullptr);
  // RGCN layer 0 (Din=532, Kpad=2144)
  k_buildX_s<<<504,256,0,stream>>>(h0, Xhi, Xlo, 532, 2144);
  gemm_mfma<1,1,64><<<dim3(8,8,1),256,0,stream>>>(Xhi, Xlo, wc0h, wc0l, hA, nullptr,
                                                  504,512,2144, 0,0,0, nullptr,nullptr,nullptr,nullptr);
  // RGCN layers 1..3 (Din=512, K=2048)
  float* hcur = hA; float* hnxt = hB;
  for (int l=0;l<3;l++){
    k_buildX_s<<<504,256,0,stream>>>(hcur, Xhi, Xlo, 512, 2048);
    gemm_mfma<1,1,64><<<dim3(8,8,1),256,0,stream>>>(Xhi, Xlo,
                                                    wc13h + (ll)l*512*2048, wc13l + (ll)l*512*2048,
                                                    hnxt, nullptr,
                                                    504,512,2048, 0,0,0, nullptr,nullptr,nullptr,nullptr);
    float* t = hcur; hcur = hnxt; hnxt = t;
  }
  // ec = h[:, :22] + e_ctx
  k_ec<<<176,256,0,stream>>>(hcur, ectx, ec);
  // fmapT bf16 [n][px][ch]
  k_fmapT<<<3872,256,0,stream>>>(ec, fmapT);
  // SE spatial branch (MFMA, plain bf16)
  gemm_mfma<0,2,64><<<dim3(8,4,4),256,0,stream>>>(w1b, nullptr, fmapT, nullptr, nullptr, s1bT,
                                                  256,484,512, 0, (ll)484*512, (ll)484*256,
                                                  nullptr, fs_b1, fs_g1, fs_be1);
  gemm_mfma<0,3,64><<<dim3(8,8,4),256,0,stream>>>(w2b, nullptr, s1bT, nullptr, sb, nullptr,
                                                  512,484,256, 0, (ll)484*256, (ll)512*484,
                                                  nullptr, fs_b2, fs_g2, fs_be2);
  // SE channel branch
  k_pool<<<8,256,0,stream>>>(ec, pooled);
  k_cb<<<4,256,0,stream>>>(pooled, fc_w1, fc_b1, fc_g1, fc_be1,
                           fc_w2, fc_b2, fc_g2, fc_be2, cbv);
  // fused -> interleaved padded bf16
  k_fused_b<<<dim3(2,64,4),256,0,stream>>>(fmapT, sb, cbv, Xint1);
  // conv stack (MFMA)
  conv5_mfma<512,256,false><<<dim3(6,4,4),256,0,stream>>>(Xint1, Wt1, cr_b1, Xint2, nullptr);
  conv5_mfma<256,256,false><<<dim3(6,4,4),256,0,stream>>>(Xint2, Wt2, cr_b2, Xint3, nullptr);
  conv5_mfma<256,512,true ><<<dim3(6,8,4),256,0,stream>>>(Xint3, Wt3, cr_b3, nullptr, out);
}

// Round 7
// 554.235 us; speedup vs baseline: 5.4431x; 1.1783x over previous
//
#include <hip/hip_runtime.h>
#include <hip/hip_bf16.h>
#include <stdint.h>

typedef long long ll;
typedef float f32x4 __attribute__((ext_vector_type(4)));
typedef __bf16 bf16x8 __attribute__((ext_vector_type(8)));
typedef __bf16 bf16x4 __attribute__((ext_vector_type(4)));

// ---------------- weight prep ----------------
// in [R][C] -> out [C][R] (split)  (W_trans 768x512 -> 512x768)
__global__ void k_castT_split(const float* __restrict__ in, __bf16* __restrict__ hi,
                              __bf16* __restrict__ lo, int R, int C){
  ll idx = (ll)blockIdx.x*256 + threadIdx.x;
  if (idx >= (ll)R*C) return;
  int r = (int)(idx % R); int c = (int)(idx / R);
  float x = in[(ll)r*C + c];
  __bf16 h = (__bf16)x;
  hi[idx] = h; lo[idx] = (__bf16)(x - (float)h);
}

// WcatT via coalesced tiled transpose. V[k][o]: k<3*Din Wrel, k<4*Din Wself, else 0.
// out [o][Kpad] split bf16. grid (Kpad/32, 16, L), block (32,8).
__global__ void k_wcatT2(const float* __restrict__ Wrel, const float* __restrict__ Wself,
                         __bf16* __restrict__ hi, __bf16* __restrict__ lo,
                         int Din, int Kpad){
  __shared__ float t[32][33];
  int l = blockIdx.z;
  const float* wr = Wrel + (ll)l*3*Din*512;
  const float* ws2 = Wself + (ll)l*Din*512;
  __bf16* hb = hi + (ll)l*512*Kpad;
  __bf16* lb = lo + (ll)l*512*Kpad;
  int k0 = blockIdx.x*32, o0 = blockIdx.y*32;
  int tx = threadIdx.x, ty = threadIdx.y;
  for (int j=ty; j<32; j+=8){
    int k = k0 + j; float v = 0.f;
    if (k < 3*Din) v = wr[(ll)k*512 + o0+tx];
    else if (k < 4*Din) v = ws2[(ll)(k-3*Din)*512 + o0+tx];
    t[j][tx] = v;
  }
  __syncthreads();
  for (int j=ty; j<32; j+=8){
    float x = t[tx][j];
    __bf16 h = (__bf16)x;
    hb[(ll)(o0+j)*Kpad + k0+tx] = h;
    lb[(ll)(o0+j)*Kpad + k0+tx] = (__bf16)(x - (float)h);
  }
}

// seqT: seq [n][1024][512] fp32 -> [n][512][1024] split bf16. grid (32,16,4), block (32,8)
__global__ void k_seqT(const float* __restrict__ seq, __bf16* __restrict__ hi,
                       __bf16* __restrict__ lo){
  __shared__ float t[32][33];
  int n = blockIdx.z;
  int r0 = blockIdx.x*32, c0 = blockIdx.y*32;
  int tx = threadIdx.x, ty = threadIdx.y;
  for (int j=ty; j<32; j+=8)
    t[j][tx] = seq[((ll)n*1024 + r0+j)*512 + c0+tx];
  __syncthreads();
  for (int j=ty; j<32; j+=8){
    float x = t[tx][j];
    __bf16 h = (__bf16)x;
    ll o = ((ll)n*512 + c0+j)*1024 + r0+tx;
    hi[o] = h; lo[o] = (__bf16)(x - (float)h);
  }
}

// conv weights: cr_w [O][C][25] fp32 -> Wt [O][25][C] bf16. one dispatch for all 3.
__global__ void wt_make_all(const float* __restrict__ w1, const float* __restrict__ w2,
                            const float* __restrict__ w3, __bf16* __restrict__ d1,
                            __bf16* __restrict__ d2, __bf16* __restrict__ d3){
  int b = blockIdx.x;
  const float* w; __bf16* dst; int C, o;
  if (b < 256){ w=w1; dst=d1; C=512; o=b; }
  else if (b < 512){ w=w2; dst=d2; C=256; o=b-256; }
  else { w=w3; dst=d3; C=256; o=b-512; }
  for (int c=threadIdx.x; c<C; c+=256){
    const float* src = w + ((size_t)o*C + c)*25;
    float v[25];
    #pragma unroll
    for (int t=0;t<25;t++) v[t] = src[t];
    #pragma unroll
    for (int t=0;t<25;t++) dst[((size_t)o*25 + t)*C + c] = (__bf16)v[t];
  }
}

// ---------------- MFMA GEMM ----------------
// A [M][K] fp32 (split to hi/lo in staging), B^T [N][K] pre-split bf16.
// 512 threads = 8 waves = 2 K-slice groups x (2M x 2N) waves. tile 64(M) x BN(N), K-step 64.
// MODE 0: Cf[M][N] = acc + (biasN?biasN:0)
// MODE 1: Cf[M][N] = relu(acc)
// MODE 2: Cb^T[N][M] = relu((acc+biasM)*g+be) bf16
// MODE 4: Xint1[e(gn)][ch] = fmapT[gn][ch] * sigmoid((acc+biasM)*g+be + cbv[ch])
template<int SPLIT, int MODE, int BN>
__global__ __launch_bounds__(512) void gemm_mfma(
    const float* __restrict__ A,
    const __bf16* __restrict__ Bhi, const __bf16* __restrict__ Blo,
    float* __restrict__ Cf, __bf16* __restrict__ Cb,
    int M, int N, int K, ll sA, ll sB, ll sC,
    const float* __restrict__ biasN, const float* __restrict__ biasM,
    const float* __restrict__ gM, const float* __restrict__ beM,
    const __bf16* __restrict__ Fm, const float* __restrict__ CBV)
{
  constexpr int NF = BN/32;
  constexpr int SL = (4096 + BN*64) * (SPLIT?2:1);
  constexpr int REDB = 256*2*NF*16;
  constexpr int LDSB = (2*SL > REDB) ? 2*SL : REDB;
  __shared__ char lds[LDSB];

  int b = blockIdx.z;
  A += sA*b; Bhi += sB*b; if (SPLIT) Blo += sB*b;

  const int tid = threadIdx.x;
  const int slice = tid>>8;          // staging & consuming K-slice
  const int tl = tid & 255;
  const int w4 = (tid>>6)&3;
  const int grp = tid>>8;
  const int l15 = tid&15, lg=(tid&63)>>4, lg16=lg*16;
  const int wave_m0=(w4>>1)*32, wave_n0=(w4&1)*(BN/2);
  const int m0 = blockIdx.y*64, n0 = blockIdx.x*BN;

  char* sA_H = lds + slice*SL;
  char* sB_H = sA_H + 4096;
  char* sA_L = sB_H + BN*64;
  char* sB_L = sA_L + 4096;

  const int sa_row=tl>>2, sa_c8=tl&3;
  const int sa_byte = sa_row*64 + ((sa_c8*16) ^ (((sa_row>>1)&3)<<4));
  const int gmA = m0 + sa_row;

  int baseA[2], baseB[NF];
  #pragma unroll
  for (int mf=0; mf<2; ++mf){
    int r = wave_m0 + mf*16 + l15;
    baseA[mf] = r*64 + (lg16 ^ (((r>>1)&3)<<4));
  }
  #pragma unroll
  for (int nf=0; nf<NF; ++nf){
    int r = wave_n0 + nf*16 + l15;
    baseB[nf] = r*64 + (lg16 ^ (((r>>1)&3)<<4));
  }

  f32x4 acc[2][NF] = {};

  for (int k0=0; k0<K; k0+=64){
    int kk = k0 + slice*32;
    __syncthreads();
    // stage A (fp32 -> split bf16)
    {
      float f[8] = {0,0,0,0,0,0,0,0};
      if (gmA < M){
        float4 p0 = *reinterpret_cast<const float4*>(A + (ll)gmA*K + kk + sa_c8*8);
        float4 p1 = *reinterpret_cast<const float4*>(A + (ll)gmA*K + kk + sa_c8*8 + 4);
        f[0]=p0.x; f[1]=p0.y; f[2]=p0.z; f[3]=p0.w;
        f[4]=p1.x; f[5]=p1.y; f[6]=p1.z; f[7]=p1.w;
      }
      bf16x8 h, l;
      #pragma unroll
      for (int j=0;j<8;j++){
        h[j] = (__bf16)f[j];
        if (SPLIT) l[j] = (__bf16)(f[j] - (float)h[j]);
      }
      *reinterpret_cast<bf16x8*>(sA_H + sa_byte) = h;
      if (SPLIT) *reinterpret_cast<bf16x8*>(sA_L + sa_byte) = l;
    }
    // stage B
    #pragma unroll
    for (int i=0;i<BN/64;i++){
      int idx = tl + i*256;
      int row = idx>>2, c8 = idx&3;
      int gn = n0 + row;
      int byte = row*64 + ((c8*16) ^ (((row>>1)&3)<<4));
      bf16x8 v = {};
      if (gn < N) v = *reinterpret_cast<const bf16x8*>(Bhi + (ll)gn*K + kk + c8*8);
      *reinterpret_cast<bf16x8*>(sB_H + byte) = v;
      if (SPLIT){
        bf16x8 vl = {};
        if (gn < N) vl = *reinterpret_cast<const bf16x8*>(Blo + (ll)gn*K + kk + c8*8);
        *reinterpret_cast<bf16x8*>(sB_L + byte) = vl;
      }
    }
    __syncthreads();
    bf16x8 aH[2], bH[NF];
    #pragma unroll
    for (int mf=0; mf<2; ++mf) aH[mf] = *reinterpret_cast<const bf16x8*>(sA_H + baseA[mf]);
    #pragma unroll
    for (int nf=0; nf<NF; ++nf) bH[nf] = *reinterpret_cast<const bf16x8*>(sB_H + baseB[nf]);
    if (SPLIT){
      bf16x8 aL[2], bL[NF];
      #pragma unroll
      for (int mf=0; mf<2; ++mf) aL[mf] = *reinterpret_cast<const bf16x8*>(sA_L + baseA[mf]);
      #pragma unroll
      for (int nf=0; nf<NF; ++nf) bL[nf] = *reinterpret_cast<const bf16x8*>(sB_L + baseB[nf]);
      #pragma unroll
      for (int mf=0; mf<2; ++mf)
        #pragma unroll
        for (int nf=0; nf<NF; ++nf){
          acc[mf][nf] = __builtin_amdgcn_mfma_f32_16x16x32_bf16(aH[mf], bH[nf], acc[mf][nf], 0,0,0);
          acc[mf][nf] = __builtin_amdgcn_mfma_f32_16x16x32_bf16(aH[mf], bL[nf], acc[mf][nf], 0,0,0);
          acc[mf][nf] = __builtin_amdgcn_mfma_f32_16x16x32_bf16(aL[mf], bH[nf], acc[mf][nf], 0,0,0);
        }
    } else {
      #pragma unroll
      for (int mf=0; mf<2; ++mf)
        #pragma unroll
        for (int nf=0; nf<NF; ++nf)
          acc[mf][nf] = __builtin_amdgcn_mfma_f32_16x16x32_bf16(aH[mf], bH[nf], acc[mf][nf], 0,0,0);
    }
  }

  // cross-group K reduction
  __syncthreads();
  if (grp==1){
    char* rp = lds + (ll)(tid-256)*(2*NF*16);
    #pragma unroll
    for (int mf=0; mf<2; ++mf)
      #pragma unroll
      for (int nf=0; nf<NF; ++nf)
        *reinterpret_cast<f32x4*>(rp + (mf*NF+nf)*16) = acc[mf][nf];
  }
  __syncthreads();
  if (grp!=0) return;
  {
    char* rp = lds + (ll)tid*(2*NF*16);
    #pragma unroll
    for (int mf=0; mf<2; ++mf)
      #pragma unroll
      for (int nf=0; nf<NF; ++nf)
        acc[mf][nf] += *reinterpret_cast<f32x4*>(rp + (mf*NF+nf)*16);
  }

  if (MODE==0 || MODE==1){
    float* C = Cf + sC*b;
    #pragma unroll
    for (int mf=0; mf<2; ++mf){
      int gmb = m0 + wave_m0 + mf*16 + lg*4;
      #pragma unroll
      for (int nf=0; nf<NF; ++nf){
        int gn = n0 + wave_n0 + nf*16 + l15;
        if (gn >= N) continue;
        float bn_ = (MODE==0 && biasN) ? biasN[gn] : 0.f;
        f32x4 a = acc[mf][nf];
        #pragma unroll
        for (int r=0;r<4;r++){
          int gm = gmb + r;
          if (gm < M){
            float v = a[r] + bn_;
            if (MODE==1) v = fmaxf(v, 0.f);
            C[(ll)gm*N + gn] = v;
          }
        }
      }
    }
  } else if (MODE==2){
    __bf16* C = Cb + sC*b;
    #pragma unroll
    for (int mf=0; mf<2; ++mf){
      int gmb = m0 + wave_m0 + mf*16 + lg*4;
      float b0=biasM[gmb], b1=biasM[gmb+1], b2=biasM[gmb+2], b3=biasM[gmb+3];
      float g0=gM[gmb], g1=gM[gmb+1], g2=gM[gmb+2], g3=gM[gmb+3];
      float e0=beM[gmb], e1=beM[gmb+1], e2=beM[gmb+2], e3=beM[gmb+3];
      #pragma unroll
      for (int nf=0; nf<NF; ++nf){
        int gn = n0 + wave_n0 + nf*16 + l15;
        if (gn >= N) continue;
        f32x4 a = acc[mf][nf];
        union { bf16x4 v; uint2 u; } pk;
        pk.v[0] = (__bf16)fmaxf((a[0]+b0)*g0+e0, 0.f);
        pk.v[1] = (__bf16)fmaxf((a[1]+b1)*g1+e1, 0.f);
        pk.v[2] = (__bf16)fmaxf((a[2]+b2)*g2+e2, 0.f);
        pk.v[3] = (__bf16)fmaxf((a[3]+b3)*g3+e3, 0.f);
        *reinterpret_cast<uint2*>(C + (ll)gn*M + gmb) = pk.u;
      }
    }
  } else { // MODE 4: fused SE2 + sigmoid gate + fmap mult -> padded interleave
    __bf16* C = Cb + sC*b;
    const __bf16* fm = Fm + (ll)b*484*512;
    const float* cb = CBV + (ll)b*512;
    #pragma unroll
    for (int mf=0; mf<2; ++mf){
      int gmb = m0 + wave_m0 + mf*16 + lg*4;
      float b0=biasM[gmb], b1=biasM[gmb+1], b2=biasM[gmb+2], b3=biasM[gmb+3];
      float g0=gM[gmb], g1=gM[gmb+1], g2=gM[gmb+2], g3=gM[gmb+3];
      float e0=beM[gmb], e1=beM[gmb+1], e2=beM[gmb+2], e3=beM[gmb+3];
      float c0=cb[gmb], c1=cb[gmb+1], c2=cb[gmb+2], c3=cb[gmb+3];
      #pragma unroll
      for (int nf=0; nf<NF; ++nf){
        int gn = n0 + wave_n0 + nf*16 + l15;
        if (gn >= N) continue;
        f32x4 a = acc[mf][nf];
        bf16x4 fmv = *reinterpret_cast<const bf16x4*>(fm + (ll)gn*512 + gmb);
        float s0 = (a[0]+b0)*g0+e0 + c0;
        float s1 = (a[1]+b1)*g1+e1 + c1;
        float s2 = (a[2]+b2)*g2+e2 + c2;
        float s3 = (a[3]+b3)*g3+e3 + c3;
        union { bf16x4 v; uint2 u; } pk;
        pk.v[0] = (__bf16)((float)fmv[0] / (1.f + expf(-s0)));
        pk.v[1] = (__bf16)((float)fmv[1] / (1.f + expf(-s1)));
        pk.v[2] = (__bf16)((float)fmv[2] / (1.f + expf(-s2)));
        pk.v[3] = (__bf16)((float)fmv[3] / (1.f + expf(-s3)));
        int py = gn/22, px = gn%22;
        int e = (py+2)*32 + px + 2;
        *reinterpret_cast<uint2*>(C + (ll)e*512 + gmb) = pk.u;
      }
    }
  }
}

// ---------------- MFMA bf16 5x5 conv (verified structure) ----------------
template<int CIN, int OCHT, bool FINAL>
__global__ __launch_bounds__(256) void conv5_mfma(
    const __bf16* __restrict__ Xg, const __bf16* __restrict__ Wt,
    const float* __restrict__ bias, __bf16* __restrict__ Xout,
    float* __restrict__ outF)
{
  __shared__ bf16x8 Xs8[272*32/8];
  __shared__ bf16x8 Ws8[5*64*32/8];
  char* xs = (char*)Xs8;
  char* wsm = (char*)Ws8;

  const int tid = threadIdx.x;
  const int l = tid & 63;
  const int l15 = l & 15, lg = l >> 4, lg16 = (l>>4)*16;
  const int w = tid >> 6;
  const int wave_o0 = (w>>1)*32;
  const int wave_p0 = (w&1)*64;
  const int b = blockIdx.z;
  const int p0 = blockIdx.x*128;
  const int o0 = blockIdx.y*64;

  int orow0 = wave_o0 + l15;
  int orow1 = wave_o0 + 16 + l15;
  int baseA0 = orow0*64 + (lg16 ^ (((orow0>>1)&3)<<4));
  int baseA1 = orow1*64 + (lg16 ^ (((orow1>>1)&3)<<4));
  int pl[4];
  #pragma unroll
  for (int pf=0; pf<4; ++pf) pl[pf] = wave_p0 + pf*16 + l15;

  f32x4 acc[2][4] = {};

  const int NCB = CIN/32;
  for (int cblk=0; cblk<NCB; ++cblk){
    __syncthreads();
    #pragma unroll
    for (int i=0;i<5;i++){
      int idx = tid + i*256;
      if (idx < 1088){
        int e = idx>>2, c8 = idx&3;
        const __bf16* g = Xg + ((size_t)(b*928 + p0 + e))*CIN + cblk*32 + c8*8;
        bf16x8 v = *reinterpret_cast<const bf16x8*>(g);
        int byte = e*64 + ((c8*16) ^ (((e>>1)&3)<<4));
        *reinterpret_cast<bf16x8*>(xs + byte) = v;
      }
    }
    for (int g5=0; g5<5; ++g5){
      if (g5>0) __syncthreads();
      #pragma unroll
      for (int i=0;i<5;i++){
        int idx = tid + i*256;
        int tapL = idx>>8, r = idx&255;
        int o = r>>2, c8 = r&3;
        const __bf16* g = Wt + ((size_t)(o0+o)*25 + (g5*5+tapL))*CIN + cblk*32 + c8*8;
        bf16x8 v = *reinterpret_cast<const bf16x8*>(g);
        int byte = tapL*4096 + o*64 + ((c8*16) ^ (((o>>1)&3)<<4));
        *reinterpret_cast<bf16x8*>(wsm + byte) = v;
      }
      __syncthreads();
      #pragma unroll
      for (int tapL=0; tapL<5; ++tapL){
        bf16x8 a0 = *reinterpret_cast<const bf16x8*>(wsm + tapL*4096 + baseA0);
        bf16x8 a1 = *reinterpret_cast<const bf16x8*>(wsm + tapL*4096 + baseA1);
        int koff = g5*32 + tapL;
        #pragma unroll
        for (int pf=0; pf<4; ++pf){
          int e = pl[pf] + koff;
          bf16x8 bv = *reinterpret_cast<const bf16x8*>(xs + e*64 + (lg16 ^ (((e>>1)&3)<<4)));
          acc[0][pf] = __builtin_amdgcn_mfma_f32_16x16x32_bf16(a0, bv, acc[0][pf], 0,0,0);
          acc[1][pf] = __builtin_amdgcn_mfma_f32_16x16x32_bf16(a1, bv, acc[1][pf], 0,0,0);
        }
      }
    }
  }

  #pragma unroll
  for (int of=0; of<2; ++of){
    int og = o0 + wave_o0 + of*16 + lg*4;
    float b0 = bias[og], b1 = bias[og+1], b2 = bias[og+2], b3 = bias[og+3];
    #pragma unroll
    for (int pf=0; pf<4; ++pf){
      int p = p0 + pl[pf];
      int py = p>>5, px = p&31;
      if (py>=22 || px>=22) continue;
      f32x4 a = acc[of][pf];
      float v0 = fmaxf(a[0]+b0, 0.f), v1 = fmaxf(a[1]+b1, 0.f);
      float v2 = fmaxf(a[2]+b2, 0.f), v3 = fmaxf(a[3]+b3, 0.f);
      if (FINAL){
        size_t base = ((size_t)b*OCHT + og)*484 + py*22 + px;
        outF[base] = v0; outF[base+484] = v1; outF[base+968] = v2; outF[base+1452] = v3;
      } else {
        union { bf16x4 v; uint2 u; } pk;
        pk.v[0] = (__bf16)v0; pk.v[1] = (__bf16)v1; pk.v[2] = (__bf16)v2; pk.v[3] = (__bf16)v3;
        int e = p + 66;
        *reinterpret_cast<uint2*>(Xout + ((size_t)(b*928 + e))*OCHT + og) = pk.u;
      }
    }
  }
}

// ---------------- fused node features (ent + link + tfeat) ----------------
__global__ void k_nodes(const float* __restrict__ seq, const float* __restrict__ att,
                        const int* __restrict__ midx, const int* __restrict__ ls_,
                        const float* __restrict__ te, float* __restrict__ h0){
  __shared__ float part[32][8];
  __shared__ float wv[32];
  int b = blockIdx.x;
  if (b < 88){
    int n = b/22, e = b%22;
    int rows[4];
    #pragma unroll
    for (int m=0;m<4;m++) rows[m] = midx[(n*22+e)*4+m];
    for (int d=threadIdx.x; d<512; d+=256){
      float v[4]; float mx = -1e30f;
      #pragma unroll
      for (int m=0;m<4;m++){
        v[m] = seq[((ll)n*1024+rows[m])*512 + d];
        h0[((ll)n*126+22+e*4+m)*532 + d] = v[m];
        mx = fmaxf(mx, v[m]);
      }
      float s = 0.f;
      #pragma unroll
      for (int m=0;m<4;m++) s += expf(v[m]-mx);
      h0[((ll)n*126+e)*532 + d] = mx + logf(s);
    }
  } else if (b < 152){
    int bb = b-88;
    int n = bb/16, l = bb%16;
    int ls = ls_[n*16+l];
    int t = threadIdx.x; int tt = t>>3, lane = t&7;
    float acc = 0.f;
    for (int i=lane; i<384; i+=8){
      int h = i>>5, s = i&31;
      acc += att[((ll)(n*12+h)*1024 + ls+s)*1024 + (ls+tt)];
    }
    part[tt][lane] = acc; __syncthreads();
    if (lane==0){
      float s2=0.f;
      #pragma unroll
      for (int q=0;q<8;q++) s2 += part[tt][q];
      wv[tt] = s2*(1.f/12.f);
    }
    __syncthreads();
    for (int d=t; d<512; d+=256){
      float a2 = 0.f;
      for (int tk=0;tk<32;tk++) a2 += wv[tk]*seq[((ll)n*1024+ls+tk)*512 + d];
      h0[((ll)n*126+110+l)*532 + d] = a2*(1.f/32.f);
    }
  } else {
    int idx = (b-152)*256 + threadIdx.x;
    if (idx < 4*126*20){
      int t = idx%20; int i = (idx/20)%126; int n = idx/(20*126);
      int ty = (i<22)?0:((i<110)?1:2);
      h0[((ll)n*126+i)*532 + 512 + t] = te[ty*20+t];
    }
  }
}

// ---------------- entity attention (single stage) ----------------
__global__ void k_ea(const float* __restrict__ att, const int* __restrict__ midx, float* __restrict__ ea){
  int n = blockIdx.x/22, e = blockIdx.x%22;
  int t = threadIdx.x;
  __shared__ float vals[1024];
  __shared__ float red[256];
  int rows[4];
  #pragma unroll
  for (int m=0;m<4;m++) rows[m] = midx[(n*22+e)*4+m];
  float local = 0.f;
  for (int c=t; c<1024; c+=256){
    float acc = 0.f;
    #pragma unroll
    for (int m=0;m<4;m++){
      const float* base = att + ((ll)n*12*1024 + rows[m])*1024 + c;
      for (int h=0;h<12;h++) acc += base[(ll)h*1024*1024];
    }
    acc *= (1.f/48.f);
    vals[c] = acc; local += acc;
  }
  red[t] = local; __syncthreads();
  for (int s=128;s>0;s>>=1){ if (t<s) red[t]+=red[t+s]; __syncthreads(); }
  float denom = red[0] + 1e-5f;
  for (int c=t; c<1024; c+=256) ea[((ll)n*22+e)*1024 + c] = vals[c]/denom;
}

// ---------------- sparse RGCN buildX (closed-form adjacency, fp32 out) ----------------
__global__ void k_buildX_s(const float* __restrict__ h, float* __restrict__ X,
                           int Din, int ldX){
  int n = blockIdx.x/126, i = blockIdx.x%126;
  const float* hb = h + (ll)n*126*Din;
  ll rowoff = (ll)(n*126+i)*ldX;
  const float inv1 = 1.f/(1.f+1e-5f), inv3 = 1.f/(3.f+1e-5f), inv4 = 1.f/(4.f+1e-5f);
  for (int d=threadIdx.x; d<Din; d+=256){
    float m0v=0.f, m1v=0.f, m2v=0.f;
    if (i < 22){
      int base = 22 + i*4;
      float s = hb[(ll)(base+0)*Din+d] + hb[(ll)(base+1)*Din+d]
              + hb[(ll)(base+2)*Din+d] + hb[(ll)(base+3)*Din+d];
      m0v = s * inv4;
    } else if (i < 110){
      int em = i-22, e = em>>2, base = 22+(e<<2);
      m0v = hb[(ll)e*Din+d] * inv1;
      float s1 = 0.f;
      #pragma unroll
      for (int m2=0;m2<4;m2++) if (base+m2 != i) s1 += hb[(ll)(base+m2)*Din+d];
      m1v = s1 * inv3;
      m2v = hb[(ll)(110+(em&15))*Din+d] * inv1;
    } else {
      int li0 = i-110;
      int cnt = (li0<8)?6:5;
      float s = 0.f;
      for (int t2=0;t2<cnt;t2++) s += hb[(ll)(22+li0+16*t2)*Din+d];
      m2v = s / ((float)cnt + 1e-5f);
    }
    float hh = hb[(ll)i*Din+d];
    X[rowoff + 0*Din + d] = m0v;
    X[rowoff + 1*Din + d] = m1v;
    X[rowoff + 2*Din + d] = m2v;
    X[rowoff + 3*Din + d] = hh;
  }
  for (int k=4*Din+threadIdx.x; k<ldX; k+=256) X[rowoff + k] = 0.f;
}

// ---------------- pairwise map / SE ----------------
__global__ void k_ec(const float* __restrict__ hfin, const float* __restrict__ ectx, float* __restrict__ ec){
  int idx = blockIdx.x*256 + threadIdx.x; // 45056 exact
  int d = idx & 511; int e = (idx>>9)%22; int n = idx/(22*512);
  ec[idx] = hfin[((ll)n*126+e)*512 + d] + ectx[idx];
}

// fmapT bf16 [n][484 px][512 ch]
__global__ void k_fmapT(const float* __restrict__ ec, __bf16* __restrict__ fmapT){
  int idx = blockIdx.x*256 + threadIdx.x; // 991232 exact
  int ch = idx & 511; int p = (idx>>9) % 484; int n = idx/(484*512);
  int i = p/22, j = p%22;
  float v = ec[((ll)n*22+i)*512+ch] * ec[((ll)n*22+j)*512+ch];
  fmapT[idx] = (__bf16)v;
}

// fused pool + channel-SE MLP
__global__ void k_poolcb(const float* __restrict__ ec,
                         const float* __restrict__ w1, const float* __restrict__ b1,
                         const float* __restrict__ g1, const float* __restrict__ be1,
                         const float* __restrict__ w2, const float* __restrict__ b2,
                         const float* __restrict__ g2, const float* __restrict__ be2,
                         float* __restrict__ cb){
  int n = blockIdx.x; int t = threadIdx.x;
  __shared__ float ps[512], t1[256];
  for (int c=t; c<512; c+=256){
    float s = 0.f;
    for (int i=0;i<22;i++) s += ec[((ll)n*22+i)*512 + c];
    ps[c] = s*s*(1.f/484.f);
  }
  __syncthreads();
  {
    float acc = 0.f;
    for (int c=0;c<512;c++) acc += w1[t*512+c]*ps[c];
    float v = g1[t]*(acc+b1[t]) + be1[t];
    t1[t] = fmaxf(v, 0.f);
  }
  __syncthreads();
  for (int o=t; o<512; o+=256){
    float acc = 0.f;
    for (int c=0;c<256;c++) acc += w2[o*256+c]*t1[c];
    cb[n*512+o] = g2[o]*(acc+b2[o]) + be2[o];
  }
}

// ---------------- launcher ----------------
extern "C" void kernel_launch(void* const* d_in, const int* in_sizes, int n_in,
                              void* d_out, int out_size, void* d_ws, size_t ws_size,
                              hipStream_t stream)
{
  (void)in_sizes; (void)n_in; (void)out_size; (void)ws_size;
  const float* seqout   = (const float*)d_in[0];
  const float* att      = (const float*)d_in[1];
  const float* W_trans  = (const float*)d_in[2];
  const float* b_trans  = (const float*)d_in[3];
  const float* type_emb = (const float*)d_in[4];
  const float* Wrel0    = (const float*)d_in[5];
  const float* Wself0   = (const float*)d_in[6];
  const float* Wrel     = (const float*)d_in[7];
  const float* Wself    = (const float*)d_in[8];
  const float* fs_w1    = (const float*)d_in[9];
  const float* fs_b1    = (const float*)d_in[10];
  const float* fs_g1    = (const float*)d_in[11];
  const float* fs_be1   = (const float*)d_in[12];
  const float* fs_w2    = (const float*)d_in[13];
  const float* fs_b2    = (const float*)d_in[14];
  const float* fs_g2    = (const float*)d_in[15];
  const float* fs_be2   = (const float*)d_in[16];
  const float* fc_w1    = (const float*)d_in[17];
  const float* fc_b1    = (const float*)d_in[18];
  const float* fc_g1    = (const float*)d_in[19];
  const float* fc_be1   = (const float*)d_in[20];
  const float* fc_w2    = (const float*)d_in[21];
  const float* fc_b2    = (const float*)d_in[22];
  const float* fc_g2    = (const float*)d_in[23];
  const float* fc_be2   = (const float*)d_in[24];
  const float* cr_w1    = (const float*)d_in[25];
  const float* cr_b1    = (const float*)d_in[26];
  const float* cr_w2    = (const float*)d_in[27];
  const float* cr_b2    = (const float*)d_in[28];
  const float* cr_w3    = (const float*)d_in[29];
  const float* cr_b3    = (const float*)d_in[30];
  const int*   midx     = (const int*)d_in[31];
  const int*   lstart   = (const int*)d_in[32];
  float* out            = (float*)d_out;

  char* wsb = (char*)d_ws;
  size_t off = 0;
  auto allocB = [&](size_t nbytes)->char*{ char* p = wsb + off; off += (nbytes + 63) & ~(size_t)63; return p; };
  float* seq   = (float*)allocB((size_t)4096*512*4);
  float* h0    = (float*)allocB((size_t)504*532*4);
  float* ea    = (float*)allocB((size_t)88*1024*4);
  float* ectx  = (float*)allocB((size_t)88*512*4);
  float* X     = (float*)allocB((size_t)504*2176*4);
  float* hA    = (float*)allocB((size_t)504*512*4);
  float* hB    = (float*)allocB((size_t)504*512*4);
  float* ec    = (float*)allocB((size_t)88*512*4);
  float* cbv   = (float*)allocB(2048*4);
  __bf16* wth  = (__bf16*)allocB((size_t)512*768*2);
  __bf16* wtl  = (__bf16*)allocB((size_t)512*768*2);
  __bf16* sqTh = (__bf16*)allocB((size_t)4*512*1024*2);
  __bf16* sqTl = (__bf16*)allocB((size_t)4*512*1024*2);
  __bf16* wc0h = (__bf16*)allocB((size_t)512*2176*2);
  __bf16* wc0l = (__bf16*)allocB((size_t)512*2176*2);
  __bf16* wc13h= (__bf16*)allocB((size_t)3*512*2048*2);
  __bf16* wc13l= (__bf16*)allocB((size_t)3*512*2048*2);
  __bf16* fmapT= (__bf16*)allocB((size_t)4*484*512*2);
  __bf16* s1bT = (__bf16*)allocB((size_t)4*484*256*2);
  __bf16* Xint1 = (__bf16*)allocB((size_t)4*928*512*2);
  __bf16* Xint2 = (__bf16*)allocB((size_t)4*928*256*2);
  __bf16* Xint3 = (__bf16*)allocB((size_t)4*928*256*2);
  __bf16* Wt1   = (__bf16*)allocB((size_t)256*25*512*2);
  __bf16* Wt2   = (__bf16*)allocB((size_t)256*25*256*2);
  __bf16* Wt3   = (__bf16*)allocB((size_t)512*25*256*2);

  // Xint1..3 are contiguous 64B-multiple allocations: one memset covers all
  (void)hipMemsetAsync(Xint1, 0, (size_t)(4*928*512 + 4*928*256 + 4*928*256)*2, stream);

  // weight prep
  wt_make_all<<<1024,256,0,stream>>>(cr_w1, cr_w2, cr_w3, Wt1, Wt2, Wt3);
  k_castT_split<<<1536,256,0,stream>>>(W_trans, wth, wtl, 768, 512);
  k_wcatT2<<<dim3(68,16,1),dim3(32,8),0,stream>>>(Wrel0, Wself0, wc0h, wc0l, 532, 2176);
  k_wcatT2<<<dim3(64,16,3),dim3(32,8),0,stream>>>(Wrel, Wself, wc13h, wc13l, 512, 2048);

  // seq = seqout @ W_trans + b_trans
  gemm_mfma<1,0,128><<<dim3(4,64,1),512,0,stream>>>(seqout, wth, wtl, seq, nullptr,
      4096,512,768, 0,0,0, b_trans,nullptr,nullptr,nullptr, nullptr,nullptr);
  // node features
  k_nodes<<<192,256,0,stream>>>(seq, att, midx, lstart, type_emb, h0);
  k_ea<<<88,256,0,stream>>>(att, midx, ea);
  // e_ctx = ea @ seq
  k_seqT<<<dim3(32,16,4),dim3(32,8),0,stream>>>(seq, sqTh, sqTl);
  gemm_mfma<1,0,64><<<dim3(8,1,4),512,0,stream>>>(ea, sqTh, sqTl, ectx, nullptr,
      22,512,1024, (ll)22*1024, (ll)512*1024, (ll)22*512,
      nullptr,nullptr,nullptr,nullptr, nullptr,nullptr);
  // RGCN layer 0 (Din=532, Kpad=2176)
  k_buildX_s<<<504,256,0,stream>>>(h0, X, 532, 2176);
  gemm_mfma<1,1,64><<<dim3(8,8,1),512,0,stream>>>(X, wc0h, wc0l, hA, nullptr,
      504,512,2176, 0,0,0, nullptr,nullptr,nullptr,nullptr, nullptr,nullptr);
  // RGCN layers 1..3 (Din=512, K=2048)
  float* hcur = hA; float* hnxt = hB;
  for (int l=0;l<3;l++){
    k_buildX_s<<<504,256,0,stream>>>(hcur, X, 512, 2048);
    gemm_mfma<1,1,64><<<dim3(8,8,1),512,0,stream>>>(X,
        wc13h + (ll)l*512*2048, wc13l + (ll)l*512*2048, hnxt, nullptr,
        504,512,2048, 0,0,0, nullptr,nullptr,nullptr,nullptr, nullptr,nullptr);
    float* t = hcur; hcur = hnxt; hnxt = t;
  }
  // ec = h[:, :22] + e_ctx
  k_ec<<<176,256,0,stream>>>(hcur, ectx, ec);
  // fmapT bf16 [n][px][ch]
  k_fmapT<<<3872,256,0,stream>>>(ec, fmapT);
  // SE spatial 1 (bf16, -> s1bT [px][256])
  gemm_mfma<0,2,64><<<dim3(8,4,4),512,0,stream>>>(fs_w1, fmapT, nullptr, nullptr, s1bT,
      256,484,512, 0, (ll)484*512, (ll)484*256,
      nullptr, fs_b1, fs_g1, fs_be1, nullptr,nullptr);
  // channel SE
  k_poolcb<<<4,256,0,stream>>>(ec, fc_w1, fc_b1, fc_g1, fc_be1,
                               fc_w2, fc_b2, fc_g2, fc_be2, cbv);
  // SE spatial 2 fused with sigmoid gate + fmap mult -> Xint1
  gemm_mfma<0,4,64><<<dim3(8,8,4),512,0,stream>>>(fs_w2, s1bT, nullptr, nullptr, Xint1,
      512,484,256, 0, (ll)484*256, (ll)928*512,
      nullptr, fs_b2, fs_g2, fs_be2, fmapT, cbv);
  // conv stack
  conv5_mfma<512,256,false><<<dim3(6,4,4),256,0,stream>>>(Xint1, Wt1, cr_b1, Xint2, nullptr);
  conv5_mfma<256,256,false><<<dim3(6,4,4),256,0,stream>>>(Xint2, Wt2, cr_b2, Xint3, nullptr);
  conv5_mfma<256,512,true ><<<dim3(6,8,4),256,0,stream>>>(Xint3, Wt3, cr_b3, nullptr, out);
}